// Round 3
// baseline (3631.339 us; speedup 1.0000x reference)
//
#include <hip/hip_runtime.h>
#include <hip/hip_bf16.h>

#define TT 256
#define NB 16
#define NTHR 512

typedef float f32x4 __attribute__((ext_vector_type(4)));
typedef short bf16x8 __attribute__((ext_vector_type(8)));

// ---------------- LDS layout (bytes) ----------------
// xpan  : [plane][16 rows][128B]  (8 u16-units, XOR-swizzled)   4 KB
// h1pan : [plane][16 rows][256B]  (12 used of 16 units)         8 KB
// h2pan : [plane][16 rows][256B]                                8 KB
// gates0: [4 planes][1536 f32]                                 24 KB
// gates1: [4 planes][1536 f32]                                 24 KB
// h2f32 : [1536 f32]                                            6 KB
#define XPAN  0
#define H1PAN 4096
#define H2PAN 12288
#define GOFF0 20480
#define GOFF1 45056
#define H2F32 69632
#define LDSZ  75776

__device__ __forceinline__ unsigned short f2bf(float f) {
    union { float f; unsigned u; } v; v.f = f;
    unsigned r = (v.u + 0x7FFFu + ((v.u >> 16) & 1u)) >> 16;
    return (unsigned short)r;
}
__device__ __forceinline__ float bf2f(unsigned short h) {
    union { unsigned u; float f; } v; v.u = ((unsigned)h) << 16;
    return v.f;
}
__device__ __forceinline__ float sigf(float x) { return 1.f / (1.f + __expf(-x)); }
__device__ __forceinline__ float tanhf_(float x) {
    float ax = fabsf(x);
    float e = __expf(-2.f * ax);
    float r = (1.f - e) / (1.f + e);
    return copysignf(r, x);
}

#define MFMA(a, b, c) __builtin_amdgcn_mfma_f32_16x16x32_bf16(a, b, c, 0, 0, 0)

// ---------------- prep: bf16 hi/lo MFMA fragment blocks (unchanged, verified) ----------------
// slot: layer0: ks*24+nt (ks 0..4); layer1: 120+ks*24+nt (ks 0..5); lo plane at +264.
// Block 512 ushort: e: i=e&7, col=(e>>3)&15, kg=e>>7; k=ks*32+kg*8+i; unitcol=nt*16+col.
__global__ void prep_frags(const float* __restrict__ Wih0, const float* __restrict__ Whh0,
                           const float* __restrict__ Wih1, const float* __restrict__ Whh1,
                           unsigned short* __restrict__ wsf) {
    int s = blockIdx.x;        // 0..263
    int e = threadIdx.x;       // 0..511
    int layer = (s >= 120);
    int rem = layer ? s - 120 : s;
    int ks = rem / 24, nt = rem % 24;
    int i = e & 7, col = (e >> 3) & 15, kg = e >> 7;
    int k = ks * 32 + kg * 8 + i;
    int cg = nt * 16 + col;
    float wv;
    if (!layer) wv = (k < 64) ? Wih0[cg * 64 + k] : Whh0[cg * 96 + (k - 64)];
    else        wv = (k < 96) ? Wih1[cg * 96 + k] : Whh1[cg * 96 + (k - 96)];
    unsigned short hi = f2bf(wv);
    float lo = wv - bf2f(hi);
    wsf[s * 512 + e] = hi;
    wsf[(264 + s) * 512 + e] = f2bf(lo);
}

// ---------------- main: 1 block = 16 rows, 8 waves, 2-engine pipeline ----------------
__global__ __launch_bounds__(NTHR, 2) void lstm_main(
    const float* __restrict__ x,
    const float* __restrict__ b0, const float* __restrict__ b1,
    const float* __restrict__ fcW1, const float* __restrict__ fcb1,
    const float* __restrict__ fcW2, const float* __restrict__ fcb2,
    const float* __restrict__ fcW3, const float* __restrict__ fcb3,
    const unsigned short* __restrict__ wsf,
    float* __restrict__ out)
{
    __shared__ __align__(16) char LDS[LDSZ];

    const int tid = threadIdx.x;
    const int lane = tid & 63;
    const int w = tid >> 6;            // wave 0..7
    const int g = w & 3;               // gate plane owned (i,f,g,o)
    const int isB = w >> 2;            // 0 = L0 engine, 1 = L1 engine
    const int l15 = lane & 15, kg = lane >> 4, r7 = l15 & 7;
    const int blk = blockIdx.x;
    const float* xblk = x + (size_t)blk * NB * TT * 64;

    // ---- persistent weight fragments (hi+lo, all in regs/AGPRs) ----
    bf16x8 Bh[6][6], Bl[6][6];
    if (!isB) {
        #pragma unroll
        for (int ks = 0; ks < 5; ++ks)
            #pragma unroll
            for (int ug = 0; ug < 6; ++ug) {
                int slot = ks * 24 + (g * 6 + ug);
                Bh[ug][ks] = *(const bf16x8*)(wsf + slot * 512 + lane * 8);
                Bl[ug][ks] = *(const bf16x8*)(wsf + (264 + slot) * 512 + lane * 8);
            }
    } else {
        #pragma unroll
        for (int ks = 0; ks < 6; ++ks)
            #pragma unroll
            for (int ug = 0; ug < 6; ++ug) {
                int slot = 120 + ks * 24 + (g * 6 + ug);
                Bh[ug][ks] = *(const bf16x8*)(wsf + slot * 512 + lane * 8);
                Bl[ug][ks] = *(const bf16x8*)(wsf + (264 + slot) * 512 + lane * 8);
            }
    }
    float bias[6];
    {
        const float* bp = isB ? b1 : b0;
        #pragma unroll
        for (int ug = 0; ug < 6; ++ug) bias[ug] = bp[g * 96 + ug * 16 + l15];
    }

    // zero h1/h2 panels (16 KB)
    {
        int* zp = (int*)(LDS + H1PAN);
        #pragma unroll 1
        for (int i = tid; i < 4096; i += NTHR) zp[i] = 0;
    }

    // stage x0
    if (tid < 128) {
        int r = tid >> 3, u8 = tid & 7;
        const float* xp = xblk + (size_t)r * TT * 64 + u8 * 8;
        f32x4 xa = *(const f32x4*)xp, xb = *(const f32x4*)(xp + 4);
        bf16x8 hv, lv;
        #pragma unroll
        for (int q = 0; q < 4; ++q) {
            unsigned short ha = f2bf(xa[q]); hv[q] = (short)ha; lv[q] = (short)f2bf(xa[q] - bf2f(ha));
            unsigned short hb = f2bf(xb[q]); hv[4 + q] = (short)hb; lv[4 + q] = (short)f2bf(xb[q] - bf2f(hb));
        }
        int off = r * 128 + ((u8 ^ (r & 7)) << 4);
        *(bf16x8*)(LDS + XPAN + off) = hv;
        *(bf16x8*)(LDS + XPAN + 2048 + off) = lv;
    }
    __syncthreads();

    float c1[3] = {0.f, 0.f, 0.f}, c2[3] = {0.f, 0.f, 0.f};
    f32x4 xr_a = {0.f, 0.f, 0.f, 0.f}, xr_b = {0.f, 0.f, 0.f, 0.f};
    char* gwp = LDS + (isB ? GOFF1 : GOFF0) + g * 6144 + l15 * 64 + kg * 16;
    const int e0 = 3 * tid;

    #pragma unroll 1
    for (int s = 0; s <= TT; ++s) {
        // issue x(s+1) global loads early; LDS-write deferred to EW phase (T14)
        if (tid < 128 && s + 1 < TT) {
            int r = tid >> 3, u8 = tid & 7;
            const float* xp = xblk + (size_t)r * TT * 64 + (size_t)(s + 1) * 64 + u8 * 8;
            xr_a = *(const f32x4*)xp; xr_b = *(const f32x4*)(xp + 4);
        }

        // ===== GEMM phase: A-waves do L0(s), B-waves do L1(s-1) =====
        if (!isB) {
            if (s < TT) {
                f32x4 a[6];
                #pragma unroll
                for (int ug = 0; ug < 6; ++ug) a[ug] = (f32x4){bias[ug], bias[ug], bias[ug], bias[ug]};
                __builtin_amdgcn_s_setprio(1);
                #pragma unroll
                for (int ks = 0; ks < 5; ++ks) {
                    bf16x8 ah, al;
                    if (ks < 2) {
                        int off = l15 * 128 + (((ks * 4 + kg) ^ r7) << 4);
                        ah = *(const bf16x8*)(LDS + XPAN + off);
                        al = *(const bf16x8*)(LDS + XPAN + 2048 + off);
                    } else {
                        int off = l15 * 256 + ((((ks - 2) * 4 + kg) ^ r7) << 4);
                        ah = *(const bf16x8*)(LDS + H1PAN + off);
                        al = *(const bf16x8*)(LDS + H1PAN + 4096 + off);
                    }
                    #pragma unroll
                    for (int ug = 0; ug < 6; ++ug) a[ug] = MFMA(ah, Bh[ug][ks], a[ug]);
                    #pragma unroll
                    for (int ug = 0; ug < 6; ++ug) a[ug] = MFMA(al, Bh[ug][ks], a[ug]);
                    #pragma unroll
                    for (int ug = 0; ug < 6; ++ug) a[ug] = MFMA(ah, Bl[ug][ks], a[ug]);
                }
                __builtin_amdgcn_s_setprio(0);
                #pragma unroll
                for (int ug = 0; ug < 6; ++ug) *(f32x4*)(gwp + ug * 1024) = a[ug];
            }
        } else {
            if (s >= 1) {
                f32x4 a[6];
                #pragma unroll
                for (int ug = 0; ug < 6; ++ug) a[ug] = (f32x4){bias[ug], bias[ug], bias[ug], bias[ug]};
                __builtin_amdgcn_s_setprio(1);
                #pragma unroll
                for (int ks = 0; ks < 6; ++ks) {
                    bf16x8 ah, al;
                    if (ks < 3) {
                        int off = l15 * 256 + (((ks * 4 + kg) ^ r7) << 4);
                        ah = *(const bf16x8*)(LDS + H1PAN + off);
                        al = *(const bf16x8*)(LDS + H1PAN + 4096 + off);
                    } else {
                        int off = l15 * 256 + ((((ks - 3) * 4 + kg) ^ r7) << 4);
                        ah = *(const bf16x8*)(LDS + H2PAN + off);
                        al = *(const bf16x8*)(LDS + H2PAN + 4096 + off);
                    }
                    #pragma unroll
                    for (int ug = 0; ug < 6; ++ug) a[ug] = MFMA(ah, Bh[ug][ks], a[ug]);
                    #pragma unroll
                    for (int ug = 0; ug < 6; ++ug) a[ug] = MFMA(al, Bh[ug][ks], a[ug]);
                    #pragma unroll
                    for (int ug = 0; ug < 6; ++ug) a[ug] = MFMA(ah, Bl[ug][ks], a[ug]);
                }
                __builtin_amdgcn_s_setprio(0);
                #pragma unroll
                for (int ug = 0; ug < 6; ++ug) *(f32x4*)(gwp + ug * 1024) = a[ug];
            }
        }
        __syncthreads();

        // ===== EW phase: all 512 threads; 3 elems per layer each =====
        if (tid < 128 && s + 1 < TT) {   // write staged x(s+1)
            int r = tid >> 3, u8 = tid & 7;
            bf16x8 hv, lv;
            #pragma unroll
            for (int q = 0; q < 4; ++q) {
                unsigned short ha = f2bf(xr_a[q]); hv[q] = (short)ha; lv[q] = (short)f2bf(xr_a[q] - bf2f(ha));
                unsigned short hb = f2bf(xr_b[q]); hv[4 + q] = (short)hb; lv[4 + q] = (short)f2bf(xr_b[q] - bf2f(hb));
            }
            int off = r * 128 + ((u8 ^ (r & 7)) << 4);
            *(bf16x8*)(LDS + XPAN + off) = hv;
            *(bf16x8*)(LDS + XPAN + 2048 + off) = lv;
        }
        if (s < TT) {   // finish L0(s) -> h1(s)
            #pragma unroll
            for (int j = 0; j < 3; ++j) {
                int e = e0 + j;
                float gi = *(const float*)(LDS + GOFF0 + e * 4);
                float gf = *(const float*)(LDS + GOFF0 + 6144 + e * 4);
                float gg = *(const float*)(LDS + GOFF0 + 12288 + e * 4);
                float go = *(const float*)(LDS + GOFF0 + 18432 + e * 4);
                float iv = sigf(gi), fv = sigf(gf), gv = tanhf_(gg), ov = sigf(go);
                float cn = fv * c1[j] + iv * gv;
                c1[j] = cn;
                float h = ov * tanhf_(cn);
                unsigned short hh = f2bf(h), hl = f2bf(h - bf2f(hh));
                int u = e >> 4, r = e & 15;
                int off = r * 256 + ((((u >> 3)) ^ (r & 7)) << 4) + (u & 7) * 2;
                *(unsigned short*)(LDS + H1PAN + off) = hh;
                *(unsigned short*)(LDS + H1PAN + 4096 + off) = hl;
            }
        }
        if (s >= 1) {   // finish L1(s-1) -> h2(s-1)
            #pragma unroll
            for (int j = 0; j < 3; ++j) {
                int e = e0 + j;
                float gi = *(const float*)(LDS + GOFF1 + e * 4);
                float gf = *(const float*)(LDS + GOFF1 + 6144 + e * 4);
                float gg = *(const float*)(LDS + GOFF1 + 12288 + e * 4);
                float go = *(const float*)(LDS + GOFF1 + 18432 + e * 4);
                float iv = sigf(gi), fv = sigf(gf), gv = tanhf_(gg), ov = sigf(go);
                float cn = fv * c2[j] + iv * gv;
                c2[j] = cn;
                float h = ov * tanhf_(cn);
                unsigned short hh = f2bf(h), hl = f2bf(h - bf2f(hh));
                int u = e >> 4, r = e & 15;
                int off = r * 256 + ((((u >> 3)) ^ (r & 7)) << 4) + (u & 7) * 2;
                *(unsigned short*)(LDS + H2PAN + off) = hh;
                *(unsigned short*)(LDS + H2PAN + 4096 + off) = hl;
                if (s == TT) ((float*)(LDS + H2F32))[e] = h;
            }
        }
        __syncthreads();
    }

    // ---------------- MLP head on exact-f32 h2(T-1): h2f[u*16 + r] ----------------
    const float* h2f = (const float*)(LDS + H2F32);
    float* z1 = (float*)(LDS + GOFF0);          // [16][96]
    float* z2 = z1 + 1536;
    if (tid < 192) {
        int u = tid % 96, half = tid / 96;
        float s0 = fcb1[u];
        for (int r = half * 8; r < half * 8 + 8; ++r) {
            float s = s0;
            #pragma unroll 4
            for (int k = 0; k < 96; ++k) s += fcW1[u * 96 + k] * h2f[k * 16 + r];
            z1[r * 96 + u] = s > 0.f ? s : 0.01f * s;
        }
    }
    __syncthreads();
    if (tid < 192) {
        int u = tid % 96, half = tid / 96;
        float s0 = fcb2[u];
        for (int r = half * 8; r < half * 8 + 8; ++r) {
            float s = s0;
            #pragma unroll 4
            for (int k = 0; k < 96; ++k) s += fcW2[u * 96 + k] * z1[r * 96 + k];
            z2[r * 96 + u] = s > 0.f ? s : 0.01f * s;
        }
    }
    __syncthreads();
    if (tid < NB) {
        float s = fcb3[0];
        #pragma unroll 4
        for (int k = 0; k < 96; ++k) s += fcW3[k] * z2[tid * 96 + k];
        out[blk * NB + tid] = s;
    }
}

extern "C" void kernel_launch(void* const* d_in, const int* in_sizes, int n_in,
                              void* d_out, int out_size, void* d_ws, size_t ws_size,
                              hipStream_t stream) {
    const float* x    = (const float*)d_in[0];
    const float* Wih0 = (const float*)d_in[1];
    const float* Whh0 = (const float*)d_in[2];
    const float* b0   = (const float*)d_in[3];
    const float* Wih1 = (const float*)d_in[4];
    const float* Whh1 = (const float*)d_in[5];
    const float* b1   = (const float*)d_in[6];
    const float* fcW1 = (const float*)d_in[7];
    const float* fcb1 = (const float*)d_in[8];
    const float* fcW2 = (const float*)d_in[9];
    const float* fcb2 = (const float*)d_in[10];
    const float* fcW3 = (const float*)d_in[11];
    const float* fcb3 = (const float*)d_in[12];

    unsigned short* wsf = (unsigned short*)d_ws;   // 528 KB fragment blocks

    prep_frags<<<264, 512, 0, stream>>>(Wih0, Whh0, Wih1, Whh1, wsf);
    lstm_main<<<4096 / NB, NTHR, 0, stream>>>(x, b0, b1, fcW1, fcb1, fcW2, fcb2,
                                              fcW3, fcb3, wsf, (float*)d_out);
}

// Round 4
// 1746.118 us; speedup vs baseline: 2.0797x; 2.0797x over previous
//
#include <hip/hip_runtime.h>
#include <hip/hip_bf16.h>

#define TT 256
#define NB 16
#define NTHR 512

typedef float f32x4 __attribute__((ext_vector_type(4)));
typedef short bf16x8 __attribute__((ext_vector_type(8)));
typedef unsigned short u16x4 __attribute__((ext_vector_type(4)));

// ---------------- LDS layout (bytes), total exactly 163840 ----------------
#define WLDS  0         // 96 KB: L1 lo-plane frags ks2..5, [g][ks-2][ug] 1-KB blocks
#define H1PAN 98304     // 8 KB: h1 [plane][16r][256B] XOR-swizzled
#define H2PAN 106496    // 8 KB: h2
#define GOFF0 114688    // 24 KB: L0 gate pre-acts [4 planes][1536 f32] (swizzled)
#define GOFF1 139264    // 24 KB: L1 gate pre-acts
#define LDSZ  163840

__device__ __forceinline__ unsigned short f2bf(float f) {
    union { float f; unsigned u; } v; v.f = f;
    unsigned r = (v.u + 0x7FFFu + ((v.u >> 16) & 1u)) >> 16;
    return (unsigned short)r;
}
__device__ __forceinline__ float bf2f(unsigned short h) {
    union { unsigned u; float f; } v; v.u = ((unsigned)h) << 16;
    return v.f;
}
__device__ __forceinline__ float sigf(float x) { return 1.f / (1.f + __expf(-x)); }
__device__ __forceinline__ float tanhf_(float x) {
    float ax = fabsf(x);
    float e = __expf(-2.f * ax);
    float r = (1.f - e) / (1.f + e);
    return copysignf(r, x);
}

#define MFMA(a, b, c) __builtin_amdgcn_mfma_f32_16x16x32_bf16(a, b, c, 0, 0, 0)

// gate-plane byte offset (swizzled) for element e = unit*16 + row
__device__ __forceinline__ int gaddr(int e) {
    int u = e >> 4, r = e & 15;
    return (u >> 4) * 1024 + (u & 15) * 64 + (((r >> 2) ^ ((u & 15) >> 2)) << 4) + (r & 3) * 4;
}
// h-panel byte offset for element e
__device__ __forceinline__ int haddr(int e) {
    int u = e >> 4, r = e & 15;
    return r * 256 + (((u >> 3) ^ (r & 7)) << 4) + (u & 7) * 2;
}

// ---------------- prep: bf16 hi/lo MFMA fragment blocks (verified r2/r3) ----------------
// slot: layer0: ks*24+nt (ks 0..4); layer1: 120+ks*24+nt (ks 0..5); lo plane at +264.
__global__ void prep_frags(const float* __restrict__ Wih0, const float* __restrict__ Whh0,
                           const float* __restrict__ Wih1, const float* __restrict__ Whh1,
                           unsigned short* __restrict__ wsf) {
    int s = blockIdx.x;        // 0..263
    int e = threadIdx.x;       // 0..511
    int layer = (s >= 120);
    int rem = layer ? s - 120 : s;
    int ks = rem / 24, nt = rem % 24;
    int i = e & 7, col = (e >> 3) & 15, kg = e >> 7;
    int k = ks * 32 + kg * 8 + i;
    int cg = nt * 16 + col;
    float wv;
    if (!layer) wv = (k < 64) ? Wih0[cg * 64 + k] : Whh0[cg * 96 + (k - 64)];
    else        wv = (k < 96) ? Wih1[cg * 96 + k] : Whh1[cg * 96 + (k - 96)];
    unsigned short hi = f2bf(wv);
    float lo = wv - bf2f(hi);
    wsf[s * 512 + e] = hi;
    wsf[(264 + s) * 512 + e] = f2bf(lo);
}

// ---------------- prepass: G0x[b,t,:] = x_t . Wih0^T + b0, stored f16 ----------------
// layout: [(blk*256+t)][tile 0..23][lane][4] u16; value = gate preact for
// (row = kg*4+q, unit = tile*16+l15)
__global__ __launch_bounds__(512) void g0x_pre(
    const float* __restrict__ x, const float* __restrict__ b0,
    const unsigned short* __restrict__ wsf, unsigned short* __restrict__ g0x)
{
    __shared__ __align__(16) char XP[2][2][2048];   // [buf][plane][16r x 128B]
    const int tid = threadIdx.x, lane = tid & 63, w = tid >> 6;
    const int l15 = lane & 15, kg = lane >> 4, r7 = l15 & 7;
    const int blk = blockIdx.x;

    bf16x8 WH[3][2], WL[3][2];
    #pragma unroll
    for (int j = 0; j < 3; ++j)
        #pragma unroll
        for (int ks = 0; ks < 2; ++ks) {
            int nt = 3 * w + j;
            WH[j][ks] = *(const bf16x8*)(wsf + (ks * 24 + nt) * 512 + lane * 8);
            WL[j][ks] = *(const bf16x8*)(wsf + (264 + ks * 24 + nt) * 512 + lane * 8);
        }
    float bias[3];
    #pragma unroll
    for (int j = 0; j < 3; ++j) bias[j] = b0[(3 * w + j) * 16 + l15];

    const int sr = tid >> 5, sk = (tid & 31) * 2, sch = sk >> 3;
    const int soff = sr * 128 + ((sch ^ (sr & 7)) << 4) + (sk & 7) * 2;
    const float* xrow = x + (size_t)(blk * 16 + sr) * TT * 64 + sk;

    // stage t=0
    {
        float v0 = xrow[0], v1 = xrow[1];
        unsigned short h0 = f2bf(v0), h1 = f2bf(v1);
        unsigned short l0 = f2bf(v0 - bf2f(h0)), l1 = f2bf(v1 - bf2f(h1));
        *(unsigned*)(&XP[0][0][0] + soff) = (unsigned)h0 | ((unsigned)h1 << 16);
        *(unsigned*)(&XP[0][1][0] + soff) = (unsigned)l0 | ((unsigned)l1 << 16);
    }
    __syncthreads();

    #pragma unroll 1
    for (int t = 0; t < TT; ++t) {
        int cur = t & 1;
        if (t + 1 < TT) {
            const float* xp = xrow + (size_t)(t + 1) * 64;
            float v0 = xp[0], v1 = xp[1];
            unsigned short h0 = f2bf(v0), h1 = f2bf(v1);
            unsigned short l0 = f2bf(v0 - bf2f(h0)), l1 = f2bf(v1 - bf2f(h1));
            *(unsigned*)(&XP[cur ^ 1][0][0] + soff) = (unsigned)h0 | ((unsigned)h1 << 16);
            *(unsigned*)(&XP[cur ^ 1][1][0] + soff) = (unsigned)l0 | ((unsigned)l1 << 16);
        }
        f32x4 acc[3];
        #pragma unroll
        for (int j = 0; j < 3; ++j) acc[j] = (f32x4){bias[j], bias[j], bias[j], bias[j]};
        #pragma unroll
        for (int ks = 0; ks < 2; ++ks) {
            int off = l15 * 128 + (((ks * 4 + kg) ^ r7) << 4);
            bf16x8 ah = *(const bf16x8*)(&XP[cur][0][0] + off);
            bf16x8 al = *(const bf16x8*)(&XP[cur][1][0] + off);
            #pragma unroll
            for (int j = 0; j < 3; ++j) acc[j] = MFMA(ah, WH[j][ks], acc[j]);
            #pragma unroll
            for (int j = 0; j < 3; ++j) acc[j] = MFMA(al, WH[j][ks], acc[j]);
            #pragma unroll
            for (int j = 0; j < 3; ++j) acc[j] = MFMA(ah, WL[j][ks], acc[j]);
        }
        #pragma unroll
        for (int j = 0; j < 3; ++j) {
            u16x4 ov;
            #pragma unroll
            for (int q = 0; q < 4; ++q) {
                union { _Float16 h; unsigned short u; } cv;
                cv.h = (_Float16)acc[j][q];
                ov[q] = cv.u;
            }
            *(u16x4*)(g0x + ((size_t)(blk * TT + t) * 24 + 3 * w + j) * 256 + lane * 4) = ov;
        }
        __syncthreads();
    }
}

// ---------------- main: 1 block = 16 rows, 8 waves, 2-engine pipeline ----------------
__global__ __launch_bounds__(NTHR, 2) void lstm_main(
    const float* __restrict__ b1,
    const float* __restrict__ fcW1, const float* __restrict__ fcb1,
    const float* __restrict__ fcW2, const float* __restrict__ fcb2,
    const float* __restrict__ fcW3, const float* __restrict__ fcb3,
    const unsigned short* __restrict__ wsf,
    const unsigned short* __restrict__ g0x,
    float* __restrict__ out)
{
    __shared__ __align__(16) char LDS[LDSZ];

    const int tid = threadIdx.x;
    const int lane = tid & 63;
    const int w = tid >> 6;            // wave 0..7
    const int g = w & 3;               // gate plane (i,f,g,o)
    const int isB = w >> 2;            // 0 = L0 engine, 1 = L1 engine
    const int l15 = lane & 15, kg = lane >> 4, r7 = l15 & 7;
    const int blk = blockIdx.x;

    // ---- unified 48-slot persistent fragment file (192 regs, both engines) ----
    bf16x8 F[48];
    #pragma unroll
    for (int ug = 0; ug < 6; ++ug)
        #pragma unroll
        for (int q = 0; q < 8; ++q) {
            int nt = g * 6 + ug;
            int slot;
            if (isB) slot = (q < 6) ? (120 + q * 24 + nt) : (384 + (q - 6) * 24 + nt);
            else     slot = (q < 3) ? ((2 + q) * 24 + nt)
                          : (q < 6) ? (264 + (q - 1) * 24 + nt)
                          : ((q - 4) * 24 + nt);          // dup filler for L0
            F[ug * 8 + q] = *(const bf16x8*)(wsf + slot * 512 + lane * 8);
        }
    float bias[6];
    #pragma unroll
    for (int ug = 0; ug < 6; ++ug) bias[ug] = b1[g * 96 + ug * 16 + l15];  // only L1 uses

    // ---- fill WLDS: L1 lo ks2..5, 96 x 1KB blocks ----
    #pragma unroll 1
    for (int i = 0; i < 12; ++i) {
        int b = w * 12 + i;
        int gq = b / 24, rem = b % 24;
        int slot = 384 + (2 + rem / 6) * 24 + gq * 6 + rem % 6;
        __builtin_amdgcn_global_load_lds(
            (const __attribute__((address_space(1))) void*)((const char*)(wsf + slot * 512) + lane * 16),
            (__attribute__((address_space(3))) void*)(LDS + WLDS + b * 1024), 16, 0, 0);
    }
    // zero h1/h2 panels
    #pragma unroll 1
    for (int i = tid; i < 4096; i += NTHR) ((int*)(LDS + H1PAN))[i] = 0;
    __syncthreads();

    float c1[3] = {0.f, 0.f, 0.f}, c2[3] = {0.f, 0.f, 0.f};
    char* gwp = LDS + (isB ? GOFF1 : GOFF0) + g * 6144 + l15 * 64 + ((kg ^ (l15 >> 2)) << 4);
    const int e0 = 3 * tid;

    #pragma unroll 1
    for (int s = 0; s <= TT; ++s) {
        // ===== GEMM phase: L0 waves do L0(s), L1 waves do L1(s-1) =====
        if (!isB) {
            if (s < TT) {
                // issue G0x loads first (consumed after MFMA loop; ~600cyc cover)
                u16x4 gx[6];
                const unsigned short* gp = g0x + ((size_t)(blk * TT + s) * 24 + g * 6) * 256 + lane * 4;
                #pragma unroll
                for (int ug = 0; ug < 6; ++ug) gx[ug] = *(const u16x4*)(gp + ug * 256);
                f32x4 acc[6];
                #pragma unroll
                for (int ug = 0; ug < 6; ++ug) acc[ug] = (f32x4){0.f, 0.f, 0.f, 0.f};
                __builtin_amdgcn_s_setprio(1);
                #pragma unroll
                for (int j = 0; j < 3; ++j) {
                    int off = l15 * 256 + (((j * 4 + kg) ^ r7) << 4);
                    bf16x8 ah = *(const bf16x8*)(LDS + H1PAN + off);
                    bf16x8 al = *(const bf16x8*)(LDS + H1PAN + 4096 + off);
                    #pragma unroll
                    for (int ug = 0; ug < 6; ++ug) acc[ug] = MFMA(ah, F[ug * 8 + j], acc[ug]);
                    #pragma unroll
                    for (int ug = 0; ug < 6; ++ug) acc[ug] = MFMA(al, F[ug * 8 + j], acc[ug]);
                    #pragma unroll
                    for (int ug = 0; ug < 6; ++ug) acc[ug] = MFMA(ah, F[ug * 8 + 3 + j], acc[ug]);
                }
                __builtin_amdgcn_s_setprio(0);
                #pragma unroll
                for (int ug = 0; ug < 6; ++ug) {
                    f32x4 t;
                    #pragma unroll
                    for (int q = 0; q < 4; ++q) {
                        union { unsigned short u; _Float16 h; } cv;
                        cv.u = gx[ug][q];
                        t[q] = acc[ug][q] + (float)cv.h;
                    }
                    *(f32x4*)(gwp + ug * 1024) = t;
                }
            }
        } else {
            if (s >= 1) {
                f32x4 acc[6];
                #pragma unroll
                for (int ug = 0; ug < 6; ++ug) acc[ug] = (f32x4){bias[ug], bias[ug], bias[ug], bias[ug]};
                __builtin_amdgcn_s_setprio(1);
                #pragma unroll
                for (int ks = 0; ks < 6; ++ks) {
                    int pan = (ks < 3) ? H1PAN : H2PAN;
                    int cc = (ks < 3) ? ks : ks - 3;
                    int off = l15 * 256 + (((cc * 4 + kg) ^ r7) << 4);
                    bf16x8 ah = *(const bf16x8*)(LDS + pan + off);
                    bf16x8 al = *(const bf16x8*)(LDS + pan + 4096 + off);
                    #pragma unroll
                    for (int ug = 0; ug < 6; ++ug) acc[ug] = MFMA(ah, F[ug * 8 + ks], acc[ug]);
                    #pragma unroll
                    for (int ug = 0; ug < 6; ++ug) acc[ug] = MFMA(al, F[ug * 8 + ks], acc[ug]);
                    if (ks < 2) {
                        #pragma unroll
                        for (int ug = 0; ug < 6; ++ug) acc[ug] = MFMA(ah, F[ug * 8 + 6 + ks], acc[ug]);
                    } else {
                        #pragma unroll
                        for (int ug = 0; ug < 6; ++ug) {
                            bf16x8 bl = *(const bf16x8*)(LDS + WLDS + (g * 24 + (ks - 2) * 6 + ug) * 1024 + lane * 16);
                            acc[ug] = MFMA(ah, bl, acc[ug]);
                        }
                    }
                }
                __builtin_amdgcn_s_setprio(0);
                #pragma unroll
                for (int ug = 0; ug < 6; ++ug) *(f32x4*)(gwp + ug * 1024) = acc[ug];
            }
        }
        __syncthreads();

        // ===== EW phase: all 512 threads, 3 elems per layer =====
        if (s < TT) {
            #pragma unroll
            for (int j = 0; j < 3; ++j) {
                int e = e0 + j, ga = gaddr(e);
                float gi = *(const float*)(LDS + GOFF0 + ga);
                float gf = *(const float*)(LDS + GOFF0 + 6144 + ga);
                float gg = *(const float*)(LDS + GOFF0 + 12288 + ga);
                float go = *(const float*)(LDS + GOFF0 + 18432 + ga);
                float iv = sigf(gi), fv = sigf(gf), gv = tanhf_(gg), ov = sigf(go);
                float cn = fv * c1[j] + iv * gv;
                c1[j] = cn;
                float h = ov * tanhf_(cn);
                unsigned short hh = f2bf(h), hl = f2bf(h - bf2f(hh));
                int off = haddr(e);
                *(unsigned short*)(LDS + H1PAN + off) = hh;
                *(unsigned short*)(LDS + H1PAN + 4096 + off) = hl;
            }
        }
        if (s >= 1) {
            #pragma unroll
            for (int j = 0; j < 3; ++j) {
                int e = e0 + j, ga = gaddr(e);
                float gi = *(const float*)(LDS + GOFF1 + ga);
                float gf = *(const float*)(LDS + GOFF1 + 6144 + ga);
                float gg = *(const float*)(LDS + GOFF1 + 12288 + ga);
                float go = *(const float*)(LDS + GOFF1 + 18432 + ga);
                float iv = sigf(gi), fv = sigf(gf), gv = tanhf_(gg), ov = sigf(go);
                float cn = fv * c2[j] + iv * gv;
                c2[j] = cn;
                float h = ov * tanhf_(cn);
                unsigned short hh = f2bf(h), hl = f2bf(h - bf2f(hh));
                int off = haddr(e);
                *(unsigned short*)(LDS + H2PAN + off) = hh;
                *(unsigned short*)(LDS + H2PAN + 4096 + off) = hl;
                if (s == TT) ((float*)(LDS + GOFF0))[e] = h;   // f32 stash (gates0 idle at s==TT)
            }
        }
        __syncthreads();
    }

    // ---------------- MLP head: h2f[u*16 + r] at GOFF0 ----------------
    const float* h2f = (const float*)(LDS + GOFF0);
    float* z1 = (float*)(LDS + GOFF1);          // [16][96]
    float* z2 = z1 + 1536;
    if (tid < 192) {
        int u = tid % 96, half = tid / 96;
        float s0 = fcb1[u];
        for (int r = half * 8; r < half * 8 + 8; ++r) {
            float s = s0;
            #pragma unroll 4
            for (int k = 0; k < 96; ++k) s += fcW1[u * 96 + k] * h2f[k * 16 + r];
            z1[r * 96 + u] = s > 0.f ? s : 0.01f * s;
        }
    }
    __syncthreads();
    if (tid < 192) {
        int u = tid % 96, half = tid / 96;
        float s0 = fcb2[u];
        for (int r = half * 8; r < half * 8 + 8; ++r) {
            float s = s0;
            #pragma unroll 4
            for (int k = 0; k < 96; ++k) s += fcW2[u * 96 + k] * z1[r * 96 + k];
            z2[r * 96 + u] = s > 0.f ? s : 0.01f * s;
        }
    }
    __syncthreads();
    if (tid < NB) {
        float s = fcb3[0];
        #pragma unroll 4
        for (int k = 0; k < 96; ++k) s += fcW3[k] * z2[tid * 96 + k];
        out[blk * NB + tid] = s;
    }
}

extern "C" void kernel_launch(void* const* d_in, const int* in_sizes, int n_in,
                              void* d_out, int out_size, void* d_ws, size_t ws_size,
                              hipStream_t stream) {
    const float* x    = (const float*)d_in[0];
    const float* Wih0 = (const float*)d_in[1];
    const float* Whh0 = (const float*)d_in[2];
    const float* b0   = (const float*)d_in[3];
    const float* Wih1 = (const float*)d_in[4];
    const float* Whh1 = (const float*)d_in[5];
    const float* b1   = (const float*)d_in[6];
    const float* fcW1 = (const float*)d_in[7];
    const float* fcb1 = (const float*)d_in[8];
    const float* fcW2 = (const float*)d_in[9];
    const float* fcb2 = (const float*)d_in[10];
    const float* fcW3 = (const float*)d_in[11];
    const float* fcb3 = (const float*)d_in[12];

    unsigned short* wsf = (unsigned short*)d_ws;                       // 528 KB frag blocks
    unsigned short* g0x = (unsigned short*)((char*)d_ws + 540672);     // 805 MB f16 G0x

    prep_frags<<<264, 512, 0, stream>>>(Wih0, Whh0, Wih1, Whh1, wsf);
    g0x_pre<<<256, 512, 0, stream>>>(x, b0, wsf, g0x);
    lstm_main<<<256, NTHR, 0, stream>>>(b1, fcW1, fcb1, fcW2, fcb2, fcW3, fcb3,
                                        wsf, g0x, (float*)d_out);
}

// Round 7
// 1659.375 us; speedup vs baseline: 2.1884x; 1.0523x over previous
//
#include <hip/hip_runtime.h>
#include <hip/hip_bf16.h>

#define TT 256
#define NB 16
#define NTHR 512

typedef float f32x4 __attribute__((ext_vector_type(4)));
typedef float f32x2 __attribute__((ext_vector_type(2)));
typedef short bf16x8 __attribute__((ext_vector_type(8)));
typedef unsigned short u16x4 __attribute__((ext_vector_type(4)));

// ---------------- LDS layout (bytes), total exactly 163840 ----------------
#define WLDS  0         // 96 KB: L1 lo-plane frags ks2..5, 1-KB blocks
#define H1PAN 98304     // 8 KB: h1 [plane][16r][256B] XOR-swizzled
#define H2PAN 106496    // 8 KB: h2
#define GOFF0 114688    // 24 KB: L0 gate pre-acts [4 planes][6144B]
#define GOFF1 139264    // 24 KB: L1 gate pre-acts
#define LDSZ  163840

__device__ __forceinline__ unsigned short f2bf(float f) {
    union { float f; unsigned u; } v; v.f = f;
    unsigned r = (v.u + 0x7FFFu + ((v.u >> 16) & 1u)) >> 16;
    return (unsigned short)r;
}
__device__ __forceinline__ float bf2f(unsigned short h) {
    union { unsigned u; float f; } v; v.u = ((unsigned)h) << 16;
    return v.f;
}
__device__ __forceinline__ float vexp2(float x) { float r; asm("v_exp_f32 %0, %1" : "=v"(r) : "v"(x)); return r; }
__device__ __forceinline__ float vrcp(float x)  { float r; asm("v_rcp_f32 %0, %1" : "=v"(r) : "v"(x)); return r; }
#define L2E 1.44269504f
__device__ __forceinline__ float sigf(float x)  { return vrcp(1.f + vexp2(x * (-L2E))); }
__device__ __forceinline__ float tanhf_(float x){ return fmaf(2.f, vrcp(1.f + vexp2(x * (-2.f * L2E))), -1.f); }

#define MFMA(a, b, c) __builtin_amdgcn_mfma_f32_16x16x32_bf16(a, b, c, 0, 0, 0)

// h-panel byte offset for (unit u, row r)
__device__ __forceinline__ int haddr(int u, int r) {
    return r * 256 + (((u >> 3) ^ (r & 7)) << 4) + (u & 7) * 2;
}

// ---------------- prep: bf16 hi/lo MFMA fragment blocks (verified r2-r4) ----------------
__global__ void prep_frags(const float* __restrict__ Wih0, const float* __restrict__ Whh0,
                           const float* __restrict__ Wih1, const float* __restrict__ Whh1,
                           unsigned short* __restrict__ wsf) {
    int s = blockIdx.x;        // 0..263
    int e = threadIdx.x;       // 0..511
    int layer = (s >= 120);
    int rem = layer ? s - 120 : s;
    int ks = rem / 24, nt = rem % 24;
    int i = e & 7, col = (e >> 3) & 15, kg = e >> 7;
    int k = ks * 32 + kg * 8 + i;
    int cg = nt * 16 + col;
    float wv;
    if (!layer) wv = (k < 64) ? Wih0[cg * 64 + k] : Whh0[cg * 96 + (k - 64)];
    else        wv = (k < 96) ? Wih1[cg * 96 + k] : Whh1[cg * 96 + (k - 96)];
    unsigned short hi = f2bf(wv);
    float lo = wv - bf2f(hi);
    wsf[s * 512 + e] = hi;
    wsf[(264 + s) * 512 + e] = f2bf(lo);
}

// ---------------- prepass: G0x[b,t] = x_t . Wih0^T + b0, stored f16 (verified r4) ----------------
__global__ __launch_bounds__(512) void g0x_pre(
    const float* __restrict__ x, const float* __restrict__ b0,
    const unsigned short* __restrict__ wsf, unsigned short* __restrict__ g0x)
{
    __shared__ __align__(16) char XP[2][2][2048];
    const int tid = threadIdx.x, lane = tid & 63, w = tid >> 6;
    const int l15 = lane & 15, kg = lane >> 4, r7 = l15 & 7;
    const int blk = blockIdx.x;

    bf16x8 WH[3][2], WL[3][2];
    #pragma unroll
    for (int j = 0; j < 3; ++j)
        #pragma unroll
        for (int ks = 0; ks < 2; ++ks) {
            int nt = 3 * w + j;
            WH[j][ks] = *(const bf16x8*)(wsf + (ks * 24 + nt) * 512 + lane * 8);
            WL[j][ks] = *(const bf16x8*)(wsf + (264 + ks * 24 + nt) * 512 + lane * 8);
        }
    float bias[3];
    #pragma unroll
    for (int j = 0; j < 3; ++j) bias[j] = b0[(3 * w + j) * 16 + l15];

    const int sr = tid >> 5, sk = (tid & 31) * 2, sch = sk >> 3;
    const int soff = sr * 128 + ((sch ^ (sr & 7)) << 4) + (sk & 7) * 2;
    const float* xrow = x + (size_t)(blk * 16 + sr) * TT * 64 + sk;

    {
        float v0 = xrow[0], v1 = xrow[1];
        unsigned short h0 = f2bf(v0), h1 = f2bf(v1);
        unsigned short l0 = f2bf(v0 - bf2f(h0)), l1 = f2bf(v1 - bf2f(h1));
        *(unsigned*)(&XP[0][0][0] + soff) = (unsigned)h0 | ((unsigned)h1 << 16);
        *(unsigned*)(&XP[0][1][0] + soff) = (unsigned)l0 | ((unsigned)l1 << 16);
    }
    __syncthreads();

    #pragma unroll 1
    for (int t = 0; t < TT; ++t) {
        int cur = t & 1;
        if (t + 1 < TT) {
            const float* xp = xrow + (size_t)(t + 1) * 64;
            float v0 = xp[0], v1 = xp[1];
            unsigned short h0 = f2bf(v0), h1 = f2bf(v1);
            unsigned short l0 = f2bf(v0 - bf2f(h0)), l1 = f2bf(v1 - bf2f(h1));
            *(unsigned*)(&XP[cur ^ 1][0][0] + soff) = (unsigned)h0 | ((unsigned)h1 << 16);
            *(unsigned*)(&XP[cur ^ 1][1][0] + soff) = (unsigned)l0 | ((unsigned)l1 << 16);
        }
        f32x4 acc[3];
        #pragma unroll
        for (int j = 0; j < 3; ++j) acc[j] = (f32x4){bias[j], bias[j], bias[j], bias[j]};
        #pragma unroll
        for (int ks = 0; ks < 2; ++ks) {
            int off = l15 * 128 + (((ks * 4 + kg) ^ r7) << 4);
            bf16x8 ah = *(const bf16x8*)(&XP[cur][0][0] + off);
            bf16x8 al = *(const bf16x8*)(&XP[cur][1][0] + off);
            #pragma unroll
            for (int j = 0; j < 3; ++j) acc[j] = MFMA(ah, WH[j][ks], acc[j]);
            #pragma unroll
            for (int j = 0; j < 3; ++j) acc[j] = MFMA(al, WH[j][ks], acc[j]);
            #pragma unroll
            for (int j = 0; j < 3; ++j) acc[j] = MFMA(ah, WL[j][ks], acc[j]);
        }
        #pragma unroll
        for (int j = 0; j < 3; ++j) {
            u16x4 ov;
            #pragma unroll
            for (int q = 0; q < 4; ++q) {
                union { _Float16 h; unsigned short u; } cv;
                cv.h = (_Float16)acc[j][q];
                ov[q] = cv.u;
            }
            *(u16x4*)(g0x + ((size_t)(blk * TT + t) * 24 + 3 * w + j) * 256 + lane * 4) = ov;
        }
        __syncthreads();
    }
}

// ---------------- main: 1 block = 16 rows, 8 waves, 2-engine pipeline ----------------
__global__ __launch_bounds__(NTHR, 2) void lstm_main(
    const float* __restrict__ b1,
    const float* __restrict__ fcW1, const float* __restrict__ fcb1,
    const float* __restrict__ fcW2, const float* __restrict__ fcb2,
    const float* __restrict__ fcW3, const float* __restrict__ fcb3,
    const unsigned short* __restrict__ wsf,
    const unsigned short* __restrict__ g0x,
    float* __restrict__ out)
{
    __shared__ __align__(16) char LDS[LDSZ];

    const int tid = threadIdx.x;
    const int lane = tid & 63;
    const int w = tid >> 6;            // wave 0..7
    const int g = w & 3;               // gate plane (i,f,g,o)
    const int isB = w >> 2;            // 0 = L0 engine, 1 = L1 engine
    const int l15 = lane & 15, kg = lane >> 4, r7 = l15 & 7;
    const int blk = blockIdx.x;

    // ---- unified 48-slot persistent fragment file ----
    bf16x8 F[48];
    #pragma unroll
    for (int ug = 0; ug < 6; ++ug)
        #pragma unroll
        for (int q = 0; q < 8; ++q) {
            int nt = g * 6 + ug;
            int slot;
            if (isB) slot = (q < 6) ? (120 + q * 24 + nt) : (384 + (q - 6) * 24 + nt);
            else     slot = (q < 3) ? ((2 + q) * 24 + nt)
                          : (q < 6) ? (264 + (q - 1) * 24 + nt)
                          : ((q - 4) * 24 + nt);
            F[ug * 8 + q] = *(const bf16x8*)(wsf + slot * 512 + lane * 8);
        }
    float bias[6];
    #pragma unroll
    for (int ug = 0; ug < 6; ++ug) bias[ug] = b1[g * 96 + ug * 16 + l15];

    // ---- fill WLDS: L1 lo ks2..5, 96 x 1KB blocks ----
    #pragma unroll 1
    for (int i = 0; i < 12; ++i) {
        int b = w * 12 + i;
        int gq = b / 24, rem = b % 24;
        int slot = 384 + (2 + rem / 6) * 24 + gq * 6 + rem % 6;
        __builtin_amdgcn_global_load_lds(
            (const __attribute__((address_space(1))) void*)((const char*)(wsf + slot * 512) + lane * 16),
            (__attribute__((address_space(3))) void*)(LDS + WLDS + b * 1024), 16, 0, 0);
    }
    #pragma unroll 1
    for (int i = tid; i < 4096; i += NTHR) ((int*)(LDS + H1PAN))[i] = 0;
    __syncthreads();

    // gate write pointer: 2-way-max bank swizzle (chunk = kg ^ ((l15>>1)&3))
    char* gwp = LDS + (isB ? GOFF1 : GOFF0) + g * 6144 + l15 * 64 + ((kg ^ ((l15 >> 1) & 3)) << 4);

    // EW state: thread owns 3 row-pair groups of ONE layer (tid<256: L0, else L1)
    const int ewp = tid & 255;
    float cst[3][2] = {{0.f, 0.f}, {0.f, 0.f}, {0.f, 0.f}};

    u16x4 gxc[6], gxn[6];
    if (!isB) {
        const unsigned short* gp = g0x + ((size_t)(blk * TT) * 24 + g * 6) * 256 + lane * 4;
        #pragma unroll
        for (int ug = 0; ug < 6; ++ug) gxc[ug] = *(const u16x4*)(gp + ug * 256);
    }

    #pragma unroll 1
    for (int s = 0; s <= TT; ++s) {
        // ===== GEMM phase =====
        if (!isB) {
            if (s < TT) {
                if (s + 1 < TT) {   // prefetch G0x one full step ahead
                    const unsigned short* gp = g0x + ((size_t)(blk * TT + s + 1) * 24 + g * 6) * 256 + lane * 4;
                    #pragma unroll
                    for (int ug = 0; ug < 6; ++ug) gxn[ug] = *(const u16x4*)(gp + ug * 256);
                }
                f32x4 acc[6];
                #pragma unroll
                for (int ug = 0; ug < 6; ++ug) acc[ug] = (f32x4){0.f, 0.f, 0.f, 0.f};
                __builtin_amdgcn_s_setprio(1);
                #pragma unroll
                for (int j = 0; j < 3; ++j) {
                    int off = l15 * 256 + (((j * 4 + kg) ^ r7) << 4);
                    bf16x8 ah = *(const bf16x8*)(LDS + H1PAN + off);
                    bf16x8 al = *(const bf16x8*)(LDS + H1PAN + 4096 + off);
                    #pragma unroll
                    for (int ug = 0; ug < 6; ++ug) acc[ug] = MFMA(ah, F[ug * 8 + j], acc[ug]);
                    #pragma unroll
                    for (int ug = 0; ug < 6; ++ug) acc[ug] = MFMA(al, F[ug * 8 + j], acc[ug]);
                    #pragma unroll
                    for (int ug = 0; ug < 6; ++ug) acc[ug] = MFMA(ah, F[ug * 8 + 3 + j], acc[ug]);
                }
                __builtin_amdgcn_s_setprio(0);
                #pragma unroll
                for (int ug = 0; ug < 6; ++ug) {
                    f32x4 t;
                    #pragma unroll
                    for (int q = 0; q < 4; ++q) {
                        union { unsigned short u; _Float16 h; } cv;
                        cv.u = gxc[ug][q];
                        t[q] = acc[ug][q] + (float)cv.h;
                    }
                    *(f32x4*)(gwp + ug * 1024) = t;
                }
                #pragma unroll
                for (int ug = 0; ug < 6; ++ug) gxc[ug] = gxn[ug];
            }
        } else {
            if (s >= 1) {
                f32x4 acc[6];
                #pragma unroll
                for (int ug = 0; ug < 6; ++ug) acc[ug] = (f32x4){bias[ug], bias[ug], bias[ug], bias[ug]};
                __builtin_amdgcn_s_setprio(1);
                #pragma unroll
                for (int ks = 0; ks < 6; ++ks) {
                    int pan = (ks < 3) ? H1PAN : H2PAN;
                    int cc = (ks < 3) ? ks : ks - 3;
                    int off = l15 * 256 + (((cc * 4 + kg) ^ r7) << 4);
                    bf16x8 ah = *(const bf16x8*)(LDS + pan + off);
                    bf16x8 al = *(const bf16x8*)(LDS + pan + 4096 + off);
                    #pragma unroll
                    for (int ug = 0; ug < 6; ++ug) acc[ug] = MFMA(ah, F[ug * 8 + ks], acc[ug]);
                    #pragma unroll
                    for (int ug = 0; ug < 6; ++ug) acc[ug] = MFMA(al, F[ug * 8 + ks], acc[ug]);
                    if (ks < 2) {
                        #pragma unroll
                        for (int ug = 0; ug < 6; ++ug) acc[ug] = MFMA(ah, F[ug * 8 + 6 + ks], acc[ug]);
                    } else {
                        #pragma unroll
                        for (int ug = 0; ug < 6; ++ug) {
                            bf16x8 bl = *(const bf16x8*)(LDS + WLDS + (g * 24 + (ks - 2) * 6 + ug) * 1024 + lane * 16);
                            acc[ug] = MFMA(ah, bl, acc[ug]);
                        }
                    }
                }
                __builtin_amdgcn_s_setprio(0);
                #pragma unroll
                for (int ug = 0; ug < 6; ++ug) *(f32x4*)(gwp + ug * 1024) = acc[ug];
            }
        }
        __syncthreads();

        // ===== EW phase: L0 half (tid<256) finishes L0(s); L1 half finishes L1(s-1) =====
        {
            bool act = isB ? (s >= 1) : (s < TT);
            if (act) {
                const int GB = isB ? GOFF1 : GOFF0;
                const int HP = isB ? H2PAN : H1PAN;
                #pragma unroll
                for (int j = 0; j < 3; ++j) {
                    int gi_ = 3 * ewp + j;
                    int u = gi_ >> 3, rp = gi_ & 7;
                    int ug = u >> 4, lu = u & 15;
                    int base = GB + ug * 1024 + lu * 64 +
                               ((((rp >> 1) ^ ((lu >> 1) & 3))) << 4) + (rp & 1) * 8;
                    f32x2 pi = *(const f32x2*)(LDS + base);
                    f32x2 pf = *(const f32x2*)(LDS + base + 6144);
                    f32x2 pg = *(const f32x2*)(LDS + base + 12288);
                    f32x2 po = *(const f32x2*)(LDS + base + 18432);
                    #pragma unroll
                    for (int e = 0; e < 2; ++e) {
                        float iv = sigf(pi[e]), fv = sigf(pf[e]);
                        float gv = tanhf_(pg[e]), ov = sigf(po[e]);
                        float cn = fmaf(fv, cst[j][e], iv * gv);
                        cst[j][e] = cn;
                        float h = ov * tanhf_(cn);
                        unsigned short hh = f2bf(h);
                        union { float f; unsigned u; } lv; lv.f = h - bf2f(hh);
                        unsigned short hl = (unsigned short)(lv.u >> 16);
                        int r = 2 * rp + e;
                        int off = haddr(u, r);
                        *(unsigned short*)(LDS + HP + off) = hh;
                        *(unsigned short*)(LDS + HP + 4096 + off) = hl;
                        if (isB && s == TT) ((float*)(LDS + GOFF0))[u * 16 + r] = h;
                    }
                }
            }
        }
        __syncthreads();
    }

    // ---------------- MLP head: h2f[u*16 + r] at GOFF0 ----------------
    const float* h2f = (const float*)(LDS + GOFF0);
    float* z1 = (float*)(LDS + GOFF1);          // [16][96]
    float* z2 = z1 + 1536;
    if (tid < 192) {
        int u = tid % 96, half = tid / 96;
        float s0 = fcb1[u];
        for (int r = half * 8; r < half * 8 + 8; ++r) {
            float s = s0;
            #pragma unroll 4
            for (int k = 0; k < 96; ++k) s += fcW1[u * 96 + k] * h2f[k * 16 + r];
            z1[r * 96 + u] = s > 0.f ? s : 0.01f * s;
        }
    }
    __syncthreads();
    if (tid < 192) {
        int u = tid % 96, half = tid / 96;
        float s0 = fcb2[u];
        for (int r = half * 8; r < half * 8 + 8; ++r) {
            float s = s0;
            #pragma unroll 4
            for (int k = 0; k < 96; ++k) s += fcW2[u * 96 + k] * z1[r * 96 + k];
            z2[r * 96 + u] = s > 0.f ? s : 0.01f * s;
        }
    }
    __syncthreads();
    if (tid < NB) {
        float s = fcb3[0];
        #pragma unroll 4
        for (int k = 0; k < 96; ++k) s += fcW3[k] * z2[tid * 96 + k];
        out[blk * NB + tid] = s;
    }
}

extern "C" void kernel_launch(void* const* d_in, const int* in_sizes, int n_in,
                              void* d_out, int out_size, void* d_ws, size_t ws_size,
                              hipStream_t stream) {
    const float* x    = (const float*)d_in[0];
    const float* Wih0 = (const float*)d_in[1];
    const float* Whh0 = (const float*)d_in[2];
    const float* b0   = (const float*)d_in[3];
    const float* Wih1 = (const float*)d_in[4];
    const float* Whh1 = (const float*)d_in[5];
    const float* b1   = (const float*)d_in[6];
    const float* fcW1 = (const float*)d_in[7];
    const float* fcb1 = (const float*)d_in[8];
    const float* fcW2 = (const float*)d_in[9];
    const float* fcb2 = (const float*)d_in[10];
    const float* fcW3 = (const float*)d_in[11];
    const float* fcb3 = (const float*)d_in[12];

    unsigned short* wsf = (unsigned short*)d_ws;                       // 528 KB frag blocks
    unsigned short* g0x = (unsigned short*)((char*)d_ws + 540672);     // 805 MB f16 G0x

    prep_frags<<<264, 512, 0, stream>>>(Wih0, Whh0, Wih1, Whh1, wsf);
    g0x_pre<<<256, 512, 0, stream>>>(x, b0, wsf, g0x);
    lstm_main<<<256, NTHR, 0, stream>>>(b1, fcW1, fcb1, fcW2, fcb2, fcW3, fcb3,
                                        wsf, g0x, (float*)d_out);
}

// Round 8
// 898.606 us; speedup vs baseline: 4.0411x; 1.8466x over previous
//
#include <hip/hip_runtime.h>
#include <hip/hip_bf16.h>

#define TT 256
#define NB 16
#define NTHR 768

typedef float f32x4 __attribute__((ext_vector_type(4)));
typedef short bf16x8 __attribute__((ext_vector_type(8)));
typedef _Float16 f16x8 __attribute__((ext_vector_type(8)));
typedef unsigned short u16x4 __attribute__((ext_vector_type(4)));

// ---------------- LDS layout (bytes) ----------------
#define H1PAN 0         // 16 KB: h1 [buf 2][plane hi/lo][16r x 256B] XOR-swizzled
#define H2PAN 16384     // 16 KB: h2 same
#define H2F32 32768     // 6 KB: final h2 f32 [u*16+r]
#define FCZ   38912     // 12 KB: FC scratch
#define LDSZ  51200

#define INV4096 0.000244140625f

__device__ __forceinline__ unsigned short f2bf(float f) {
    union { float f; unsigned u; } v; v.f = f;
    unsigned r = (v.u + 0x7FFFu + ((v.u >> 16) & 1u)) >> 16;
    return (unsigned short)r;
}
__device__ __forceinline__ float bf2f(unsigned short h) {
    union { unsigned u; float f; } v; v.u = ((unsigned)h) << 16;
    return v.f;
}
__device__ __forceinline__ float vexp2(float x) { float r; asm("v_exp_f32 %0, %1" : "=v"(r) : "v"(x)); return r; }
__device__ __forceinline__ float vrcp(float x)  { float r; asm("v_rcp_f32 %0, %1" : "=v"(r) : "v"(x)); return r; }
#define L2E 1.44269504f
__device__ __forceinline__ float sigf(float x)  { return vrcp(1.f + vexp2(x * (-L2E))); }
__device__ __forceinline__ float tanhf_(float x){ return fmaf(2.f, vrcp(1.f + vexp2(x * (-2.f * L2E))), -1.f); }

#define MFMA(a, b, c)   __builtin_amdgcn_mfma_f32_16x16x32_bf16(a, b, c, 0, 0, 0)
#define MFMA16(a, b, c) __builtin_amdgcn_mfma_f32_16x16x32_f16(a, b, c, 0, 0, 0)

__device__ __forceinline__ unsigned short f2h_bits(float f) {
    union { _Float16 h; unsigned short u; } cv; cv.h = (_Float16)f; return cv.u;
}
__device__ __forceinline__ float h2f_val(unsigned short u) {
    union { unsigned short u; _Float16 h; } cv; cv.u = u; return (float)cv.h;
}

// ---------------- prep: bf16 hi/lo fragment blocks (verified r2-r7; prepass uses ks0,1) ----------------
__global__ void prep_frags(const float* __restrict__ Wih0, const float* __restrict__ Whh0,
                           const float* __restrict__ Wih1, const float* __restrict__ Whh1,
                           unsigned short* __restrict__ wsf) {
    int s = blockIdx.x;        // 0..263
    int e = threadIdx.x;       // 0..511
    int layer = (s >= 120);
    int rem = layer ? s - 120 : s;
    int ks = rem / 24, nt = rem % 24;
    int i = e & 7, col = (e >> 3) & 15, kg = e >> 7;
    int k = ks * 32 + kg * 8 + i;
    int cg = nt * 16 + col;
    float wv;
    if (!layer) wv = (k < 64) ? Wih0[cg * 64 + k] : Whh0[cg * 96 + (k - 64)];
    else        wv = (k < 96) ? Wih1[cg * 96 + k] : Whh1[cg * 96 + (k - 96)];
    unsigned short hi = f2bf(wv);
    float lo = wv - bf2f(hi);
    wsf[s * 512 + e] = hi;
    wsf[(264 + s) * 512 + e] = f2bf(lo);
}

// ---------------- prep16: f16 hi-only fragments for main kernel ----------------
// slot: L0 (h-part): j*24+nt, j 0..2 (ks=2+j, k=64..159); L1: 72 + ks*24 + nt, ks 0..5
__global__ void prep_frags16(const float* __restrict__ Whh0,
                             const float* __restrict__ Wih1, const float* __restrict__ Whh1,
                             unsigned short* __restrict__ wsf2) {
    int s = blockIdx.x;        // 0..215
    int e = threadIdx.x;       // 0..511
    int i = e & 7, col = (e >> 3) & 15, kg = e >> 7;
    float wv;
    if (s < 72) {
        int ks = 2 + s / 24, nt = s % 24;
        int k = ks * 32 + kg * 8 + i, cg = nt * 16 + col;
        wv = Whh0[cg * 96 + (k - 64)];
    } else {
        int s2 = s - 72;
        int ks = s2 / 24, nt = s2 % 24;
        int k = ks * 32 + kg * 8 + i, cg = nt * 16 + col;
        wv = (k < 96) ? Wih1[cg * 96 + k] : Whh1[cg * 96 + (k - 96)];
    }
    wsf2[s * 512 + e] = f2h_bits(wv);
}

// ---------------- prepass: G0x[b,t] = x_t . Wih0^T + b0, stored f16 (verified r4/r7) ----------------
__global__ __launch_bounds__(512) void g0x_pre(
    const float* __restrict__ x, const float* __restrict__ b0,
    const unsigned short* __restrict__ wsf, unsigned short* __restrict__ g0x)
{
    __shared__ __align__(16) char XP[2][2][2048];
    const int tid = threadIdx.x, lane = tid & 63, w = tid >> 6;
    const int l15 = lane & 15, kg = lane >> 4, r7 = l15 & 7;
    const int blk = blockIdx.x;

    bf16x8 WH[3][2], WL[3][2];
    #pragma unroll
    for (int j = 0; j < 3; ++j)
        #pragma unroll
        for (int ks = 0; ks < 2; ++ks) {
            int nt = 3 * w + j;
            WH[j][ks] = *(const bf16x8*)(wsf + (ks * 24 + nt) * 512 + lane * 8);
            WL[j][ks] = *(const bf16x8*)(wsf + (264 + ks * 24 + nt) * 512 + lane * 8);
        }
    float bias[3];
    #pragma unroll
    for (int j = 0; j < 3; ++j) bias[j] = b0[(3 * w + j) * 16 + l15];

    const int sr = tid >> 5, sk = (tid & 31) * 2, sch = sk >> 3;
    const int soff = sr * 128 + ((sch ^ (sr & 7)) << 4) + (sk & 7) * 2;
    const float* xrow = x + (size_t)(blk * 16 + sr) * TT * 64 + sk;

    {
        float v0 = xrow[0], v1 = xrow[1];
        unsigned short h0 = f2bf(v0), h1 = f2bf(v1);
        unsigned short l0 = f2bf(v0 - bf2f(h0)), l1 = f2bf(v1 - bf2f(h1));
        *(unsigned*)(&XP[0][0][0] + soff) = (unsigned)h0 | ((unsigned)h1 << 16);
        *(unsigned*)(&XP[0][1][0] + soff) = (unsigned)l0 | ((unsigned)l1 << 16);
    }
    __syncthreads();

    #pragma unroll 1
    for (int t = 0; t < TT; ++t) {
        int cur = t & 1;
        if (t + 1 < TT) {
            const float* xp = xrow + (size_t)(t + 1) * 64;
            float v0 = xp[0], v1 = xp[1];
            unsigned short h0 = f2bf(v0), h1 = f2bf(v1);
            unsigned short l0 = f2bf(v0 - bf2f(h0)), l1 = f2bf(v1 - bf2f(h1));
            *(unsigned*)(&XP[cur ^ 1][0][0] + soff) = (unsigned)h0 | ((unsigned)h1 << 16);
            *(unsigned*)(&XP[cur ^ 1][1][0] + soff) = (unsigned)l0 | ((unsigned)l1 << 16);
        }
        f32x4 acc[3];
        #pragma unroll
        for (int j = 0; j < 3; ++j) acc[j] = (f32x4){bias[j], bias[j], bias[j], bias[j]};
        #pragma unroll
        for (int ks = 0; ks < 2; ++ks) {
            int off = l15 * 128 + (((ks * 4 + kg) ^ r7) << 4);
            bf16x8 ah = *(const bf16x8*)(&XP[cur][0][0] + off);
            bf16x8 al = *(const bf16x8*)(&XP[cur][1][0] + off);
            #pragma unroll
            for (int j = 0; j < 3; ++j) acc[j] = MFMA(ah, WH[j][ks], acc[j]);
            #pragma unroll
            for (int j = 0; j < 3; ++j) acc[j] = MFMA(al, WH[j][ks], acc[j]);
            #pragma unroll
            for (int j = 0; j < 3; ++j) acc[j] = MFMA(ah, WL[j][ks], acc[j]);
        }
        #pragma unroll
        for (int j = 0; j < 3; ++j) {
            u16x4 ov;
            #pragma unroll
            for (int q = 0; q < 4; ++q) ov[q] = f2h_bits(acc[j][q]);
            *(u16x4*)(g0x + ((size_t)(blk * TT + t) * 24 + 3 * w + j) * 256 + lane * 4) = ov;
        }
        __syncthreads();
    }
}

// ---------------- main: 12 waves (6 L0-engine + 6 L1-engine), in-register EW, 1 barrier/step ----------------
__global__ __launch_bounds__(NTHR, 3) void lstm_main(
    const float* __restrict__ b1,
    const float* __restrict__ fcW1, const float* __restrict__ fcb1,
    const float* __restrict__ fcW2, const float* __restrict__ fcb2,
    const float* __restrict__ fcW3, const float* __restrict__ fcb3,
    const unsigned short* __restrict__ wsf2,
    const unsigned short* __restrict__ g0x,
    float* __restrict__ out)
{
    __shared__ __align__(16) char LDS[LDSZ];

    const int tid = threadIdx.x;
    const int lane = tid & 63;
    const int w = tid >> 6;                  // 0..11
    const int isB = (w ^ (w >> 2)) & 1;      // engine: 0=L0, 1=L1 (SIMD-balanced mix)
    const int ub = w >> 1;                   // unit block 0..5 (16 units each)
    const int l15 = lane & 15, kg = lane >> 4, r7 = l15 & 7;
    const int blk = blockIdx.x;

    // zero h panels (32 KB)
    #pragma unroll 1
    for (int i = tid; i < 8192; i += NTHR) ((int*)(LDS + H1PAN))[i] = 0;
    __syncthreads();

    const int cb = ub * 2 + (l15 >> 3);      // write chunk base
    const int lo2 = (l15 & 7) * 2;

    if (!isB) {
        // ================= L0 engine: computes L0(s), all 4 gates of unit block ub =================
        f16x8 F0[4][3];
        #pragma unroll
        for (int g = 0; g < 4; ++g)
            #pragma unroll
            for (int j = 0; j < 3; ++j)
                F0[g][j] = *(const f16x8*)(wsf2 + (j * 24 + g * 6 + ub) * 512 + lane * 8);

        const unsigned short* gbase = g0x + (size_t)(blk * TT) * 24 * 256;
        u16x4 gxc[4], gxn[4];
        #pragma unroll
        for (int g = 0; g < 4; ++g) gxc[g] = *(const u16x4*)(gbase + (g * 6 + ub) * 256 + lane * 4);

        f32x4 c1 = {0.f, 0.f, 0.f, 0.f};

        #pragma unroll 1
        for (int s = 0; s <= TT; ++s) {
            if (s < TT) {
                if (s + 1 < TT) {
                    const unsigned short* gp = gbase + (size_t)(s + 1) * 6144;
                    #pragma unroll
                    for (int g = 0; g < 4; ++g) gxn[g] = *(const u16x4*)(gp + (g * 6 + ub) * 256 + lane * 4);
                }
                const char* h1r = LDS + H1PAN + (((s & 1) ^ 1) << 13);
                f32x4 aH[4], aL[4];
                #pragma unroll
                for (int g = 0; g < 4; ++g) { aH[g] = (f32x4){0.f,0.f,0.f,0.f}; aL[g] = (f32x4){0.f,0.f,0.f,0.f}; }
                __builtin_amdgcn_s_setprio(1);
                #pragma unroll
                for (int j = 0; j < 3; ++j) {
                    int off = l15 * 256 + (((j * 4 + kg) ^ r7) << 4);
                    f16x8 ah = *(const f16x8*)(h1r + off);
                    f16x8 al = *(const f16x8*)(h1r + 4096 + off);
                    #pragma unroll
                    for (int g = 0; g < 4; ++g) aH[g] = MFMA16(ah, F0[g][j], aH[g]);
                    #pragma unroll
                    for (int g = 0; g < 4; ++g) aL[g] = MFMA16(al, F0[g][j], aL[g]);
                }
                __builtin_amdgcn_s_setprio(0);
                // in-register EW -> h1(s)
                char* h1w = LDS + H1PAN + ((s & 1) << 13);
                #pragma unroll
                for (int q = 0; q < 4; ++q) {
                    float pi = aH[0][q] + aL[0][q] * INV4096 + h2f_val(gxc[0][q]);
                    float pf = aH[1][q] + aL[1][q] * INV4096 + h2f_val(gxc[1][q]);
                    float pg = aH[2][q] + aL[2][q] * INV4096 + h2f_val(gxc[2][q]);
                    float po = aH[3][q] + aL[3][q] * INV4096 + h2f_val(gxc[3][q]);
                    float iv = sigf(pi), fv = sigf(pf), gv = tanhf_(pg), ov = sigf(po);
                    float cn = fmaf(fv, c1[q], iv * gv);
                    c1[q] = cn;
                    float h = ov * tanhf_(cn);
                    _Float16 hh = (_Float16)h;
                    float rem = (h - (float)hh) * 4096.f;
                    unsigned short hu, lu;
                    { union { _Float16 h; unsigned short u; } cv; cv.h = hh; hu = cv.u; }
                    lu = f2h_bits(rem);
                    int r_ = kg * 4 + q;
                    int off = r_ * 256 + ((cb ^ (r_ & 7)) << 4) + lo2;
                    *(unsigned short*)(h1w + off) = hu;
                    *(unsigned short*)(h1w + 4096 + off) = lu;
                }
                #pragma unroll
                for (int g = 0; g < 4; ++g) gxc[g] = gxn[g];
            }
            __syncthreads();
        }
    } else {
        // ================= L1 engine: computes L1(s-1) =================
        f16x8 F1[4][6];
        #pragma unroll
        for (int g = 0; g < 4; ++g)
            #pragma unroll
            for (int j = 0; j < 6; ++j)
                F1[g][j] = *(const f16x8*)(wsf2 + (72 + j * 24 + g * 6 + ub) * 512 + lane * 8);
        float bias[4];
        #pragma unroll
        for (int g = 0; g < 4; ++g) bias[g] = b1[g * 96 + ub * 16 + l15];

        f32x4 c2 = {0.f, 0.f, 0.f, 0.f};

        #pragma unroll 1
        for (int s = 0; s <= TT; ++s) {
            if (s >= 1) {
                const char* h1r = LDS + H1PAN + (((s & 1) ^ 1) << 13);   // h1(s-1)
                const char* h2r = LDS + H2PAN + ((s & 1) << 13);         // h2(s-2)
                f32x4 aH[4], aL[4];
                #pragma unroll
                for (int g = 0; g < 4; ++g) { aH[g] = (f32x4){bias[g],bias[g],bias[g],bias[g]}; aL[g] = (f32x4){0.f,0.f,0.f,0.f}; }
                __builtin_amdgcn_s_setprio(1);
                #pragma unroll
                for (int j = 0; j < 6; ++j) {
                    const char* pan = (j < 3) ? h1r : h2r;
                    int cc = (j < 3) ? j : j - 3;
                    int off = l15 * 256 + (((cc * 4 + kg) ^ r7) << 4);
                    f16x8 ah = *(const f16x8*)(pan + off);
                    f16x8 al = *(const f16x8*)(pan + 4096 + off);
                    #pragma unroll
                    for (int g = 0; g < 4; ++g) aH[g] = MFMA16(ah, F1[g][j], aH[g]);
                    #pragma unroll
                    for (int g = 0; g < 4; ++g) aL[g] = MFMA16(al, F1[g][j], aL[g]);
                }
                __builtin_amdgcn_s_setprio(0);
                // in-register EW -> h2(s-1)
                char* h2w = LDS + H2PAN + ((~s & 1) << 13);
                #pragma unroll
                for (int q = 0; q < 4; ++q) {
                    float pi = aH[0][q] + aL[0][q] * INV4096;
                    float pf = aH[1][q] + aL[1][q] * INV4096;
                    float pg = aH[2][q] + aL[2][q] * INV4096;
                    float po = aH[3][q] + aL[3][q] * INV4096;
                    float iv = sigf(pi), fv = sigf(pf), gv = tanhf_(pg), ov = sigf(po);
                    float cn = fmaf(fv, c2[q], iv * gv);
                    c2[q] = cn;
                    float h = ov * tanhf_(cn);
                    _Float16 hh = (_Float16)h;
                    float rem = (h - (float)hh) * 4096.f;
                    unsigned short hu, lu;
                    { union { _Float16 h; unsigned short u; } cv; cv.h = hh; hu = cv.u; }
                    lu = f2h_bits(rem);
                    int r_ = kg * 4 + q;
                    int off = r_ * 256 + ((cb ^ (r_ & 7)) << 4) + lo2;
                    *(unsigned short*)(h2w + off) = hu;
                    *(unsigned short*)(h2w + 4096 + off) = lu;
                    if (s == TT)
                        ((float*)(LDS + H2F32))[(ub * 16 + l15) * 16 + r_] = h;
                }
            }
            __syncthreads();
        }
    }
    __syncthreads();

    // ---------------- MLP head on f32 h2(T-1): h2f[u*16 + r] ----------------
    const float* h2f = (const float*)(LDS + H2F32);
    float* z1 = (float*)(LDS + FCZ);          // [16][96]
    float* z2 = z1 + 1536;
    if (tid < 192) {
        int u = tid % 96, half = tid / 96;
        float s0 = fcb1[u];
        for (int r = half * 8; r < half * 8 + 8; ++r) {
            float s = s0;
            #pragma unroll 4
            for (int k = 0; k < 96; ++k) s += fcW1[u * 96 + k] * h2f[k * 16 + r];
            z1[r * 96 + u] = s > 0.f ? s : 0.01f * s;
        }
    }
    __syncthreads();
    if (tid < 192) {
        int u = tid % 96, half = tid / 96;
        float s0 = fcb2[u];
        for (int r = half * 8; r < half * 8 + 8; ++r) {
            float s = s0;
            #pragma unroll 4
            for (int k = 0; k < 96; ++k) s += fcW2[u * 96 + k] * z1[r * 96 + k];
            z2[r * 96 + u] = s > 0.f ? s : 0.01f * s;
        }
    }
    __syncthreads();
    if (tid < NB) {
        float s = fcb3[0];
        #pragma unroll 4
        for (int k = 0; k < 96; ++k) s += fcW3[k] * z2[tid * 96 + k];
        out[blk * NB + tid] = s;
    }
}

extern "C" void kernel_launch(void* const* d_in, const int* in_sizes, int n_in,
                              void* d_out, int out_size, void* d_ws, size_t ws_size,
                              hipStream_t stream) {
    const float* x    = (const float*)d_in[0];
    const float* Wih0 = (const float*)d_in[1];
    const float* Whh0 = (const float*)d_in[2];
    const float* b0   = (const float*)d_in[3];
    const float* Wih1 = (const float*)d_in[4];
    const float* Whh1 = (const float*)d_in[5];
    const float* b1   = (const float*)d_in[6];
    const float* fcW1 = (const float*)d_in[7];
    const float* fcb1 = (const float*)d_in[8];
    const float* fcW2 = (const float*)d_in[9];
    const float* fcb2 = (const float*)d_in[10];
    const float* fcW3 = (const float*)d_in[11];
    const float* fcb3 = (const float*)d_in[12];

    unsigned short* wsf  = (unsigned short*)d_ws;            // 528 KB bf16 frag blocks
    unsigned short* wsf2 = wsf + 312 * 512;                  // 216 KB f16 frags (overlays unused bf16 slots)
    unsigned short* g0x  = (unsigned short*)((char*)d_ws + 540672);   // 805 MB f16 G0x

    prep_frags<<<264, 512, 0, stream>>>(Wih0, Whh0, Wih1, Whh1, wsf);
    prep_frags16<<<216, 512, 0, stream>>>(Whh0, Wih1, Whh1, wsf2);
    g0x_pre<<<256, 512, 0, stream>>>(x, b0, wsf, g0x);
    lstm_main<<<256, NTHR, 0, stream>>>(b1, fcW1, fcb1, fcW2, fcb2, fcW3, fcb3,
                                        wsf2, g0x, (float*)d_out);
}

// Round 9
// 448.705 us; speedup vs baseline: 8.0929x; 2.0027x over previous
//
#include <hip/hip_runtime.h>
#include <hip/hip_bf16.h>

#define TT 256
#define NB 16
#define NTHR 768

typedef float f32x4 __attribute__((ext_vector_type(4)));
typedef _Float16 f16x8 __attribute__((ext_vector_type(8)));

// ---------------- LDS layout (bytes) ----------------
#define XPAN  0         // 8 KB: x [2 buf][2 plane hi/lo][16r x 128B] XOR-swizzled
#define H1PAN 8192      // 8 KB: h1 [2 buf][16r x 256B] single f16, XOR-swizzled
#define H2PAN 16384     // 8 KB: h2 same
#define H2F32 24576     // 6 KB: final h2 f32 [u*16+r]
#define FCZ   30720     // 12 KB: FC scratch
#define LDSZ  43008

#define INV4096 0.000244140625f

__device__ __forceinline__ float vexp2(float x) { float r; asm("v_exp_f32 %0, %1" : "=v"(r) : "v"(x)); return r; }
__device__ __forceinline__ float vrcp(float x)  { float r; asm("v_rcp_f32 %0, %1" : "=v"(r) : "v"(x)); return r; }
#define L2E 1.44269504f
__device__ __forceinline__ float sigf(float x)  { return vrcp(1.f + vexp2(x * (-L2E))); }
__device__ __forceinline__ float tanhf_(float x){ return fmaf(2.f, vrcp(1.f + vexp2(x * (-2.f * L2E))), -1.f); }

#define MFMA16(a, b, c) __builtin_amdgcn_mfma_f32_16x16x32_f16(a, b, c, 0, 0, 0)

__device__ __forceinline__ unsigned short f2h_bits(float f) {
    union { _Float16 h; unsigned short u; } cv; cv.h = (_Float16)f; return cv.u;
}

// ---------------- prep16: all f16 weight fragments ----------------
// Block layout (verified r2-r8): elem e: i=e&7, col=(e>>3)&15, kg=e>>7;
// k = ks*32+kg*8+i; unit = nt*16+col. Lane l reads [l*8 .. l*8+8) -> B-frag.
// slots: L0-x: ks*24+nt (ks 0..1, Wih0); L0-h: 48 + j*24+nt (j 0..2, Whh0);
//        L1:   120 + j*24+nt (j 0..5, Wih1|Whh1)
__global__ void prep_frags16(const float* __restrict__ Wih0, const float* __restrict__ Whh0,
                             const float* __restrict__ Wih1, const float* __restrict__ Whh1,
                             unsigned short* __restrict__ wsf2) {
    int s = blockIdx.x;        // 0..263
    int e = threadIdx.x;       // 0..511
    int i = e & 7, col = (e >> 3) & 15, kg = e >> 7;
    float wv;
    if (s < 48) {
        int ks = s / 24, nt = s % 24;
        int k = ks * 32 + kg * 8 + i, cg = nt * 16 + col;
        wv = Wih0[cg * 64 + k];
    } else if (s < 120) {
        int j = (s - 48) / 24, nt = (s - 48) % 24;
        int k = j * 32 + kg * 8 + i, cg = nt * 16 + col;
        wv = Whh0[cg * 96 + k];
    } else {
        int s2 = s - 120;
        int j = s2 / 24, nt = s2 % 24;
        int k = j * 32 + kg * 8 + i, cg = nt * 16 + col;
        wv = (k < 96) ? Wih1[cg * 96 + k] : Whh1[cg * 96 + (k - 96)];
    }
    wsf2[s * 512 + e] = f2h_bits(wv);
}

// ---------------- main: 12 waves (6 L0 + 6 L1), fused x-GEMM, in-register EW ----------------
__global__ __launch_bounds__(NTHR, 3) void lstm_main(
    const float* __restrict__ x,
    const float* __restrict__ b0, const float* __restrict__ b1,
    const float* __restrict__ fcW1, const float* __restrict__ fcb1,
    const float* __restrict__ fcW2, const float* __restrict__ fcb2,
    const float* __restrict__ fcW3, const float* __restrict__ fcb3,
    const unsigned short* __restrict__ wsf2,
    float* __restrict__ out)
{
    __shared__ __align__(16) char LDS[LDSZ];

    const int tid = threadIdx.x;
    const int lane = tid & 63;
    const int w = tid >> 6;                  // 0..11
    const int isB = (w ^ (w >> 2)) & 1;      // engine: 0=L0, 1=L1 (SIMD-balanced)
    const int ub = w >> 1;                   // unit block 0..5
    const int l15 = lane & 15, kg = lane >> 4, r7 = l15 & 7;
    const int blk = blockIdx.x;
    const float* xblk = x + (size_t)blk * NB * TT * 64;

    // zero h panels (16 KB)
    #pragma unroll 1
    for (int i = tid; i < 4096; i += NTHR) ((int*)(LDS + H1PAN))[i] = 0;

    const int cb = ub * 2 + (l15 >> 3);      // h-write chunk base
    const int lo2 = (l15 & 7) * 2;

    if (!isB) {
        // ================= L0 engine =================
        const bool stg = (w == 0 || w == 2);           // x-staging waves (both L0)
        const int st = (w == 2) ? lane + 64 : lane;    // 0..127
        const int sr = st >> 3, su = st & 7;
        const float* xsrc = xblk + (size_t)sr * TT * 64 + su * 8;
        const int xoff = sr * 128 + ((su ^ (sr & 7)) << 4);

        f32x4 xa, xb;
        // stage x(0) into XPAN buf 0
        if (stg) {
            xa = *(const f32x4*)xsrc; xb = *(const f32x4*)(xsrc + 4);
            f16x8 hv, lv;
            #pragma unroll
            for (int q = 0; q < 4; ++q) {
                hv[q] = (_Float16)xa[q];     lv[q] = (_Float16)((xa[q] - (float)hv[q]) * 4096.f);
                hv[4+q] = (_Float16)xb[q];   lv[4+q] = (_Float16)((xb[q] - (float)hv[4+q]) * 4096.f);
            }
            *(f16x8*)(LDS + XPAN + xoff) = hv;
            *(f16x8*)(LDS + XPAN + 2048 + xoff) = lv;
        }

        f16x8 F0x[4][2], F0h[4][3];
        #pragma unroll
        for (int g = 0; g < 4; ++g) {
            #pragma unroll
            for (int ks = 0; ks < 2; ++ks)
                F0x[g][ks] = *(const f16x8*)(wsf2 + (ks * 24 + g * 6 + ub) * 512 + lane * 8);
            #pragma unroll
            for (int j = 0; j < 3; ++j)
                F0h[g][j] = *(const f16x8*)(wsf2 + (48 + j * 24 + g * 6 + ub) * 512 + lane * 8);
        }
        float bias[4];
        #pragma unroll
        for (int g = 0; g < 4; ++g) bias[g] = b0[g * 96 + ub * 16 + l15];

        f32x4 c1 = {0.f, 0.f, 0.f, 0.f};
        __syncthreads();

        #pragma unroll 1
        for (int s = 0; s <= TT; ++s) {
            if (s < TT) {
                if (stg && s + 1 < TT) {   // issue x(s+1) loads early (T14)
                    const float* xp = xsrc + (size_t)(s + 1) * 64;
                    xa = *(const f32x4*)xp; xb = *(const f32x4*)(xp + 4);
                }
                const char* xr  = LDS + XPAN + ((s & 1) << 12);
                const char* h1r = LDS + H1PAN + (((s & 1) ^ 1) << 12);
                f32x4 aH[4], aL[4];
                #pragma unroll
                for (int g = 0; g < 4; ++g) {
                    aH[g] = (f32x4){bias[g], bias[g], bias[g], bias[g]};
                    aL[g] = (f32x4){0.f, 0.f, 0.f, 0.f};
                }
                __builtin_amdgcn_s_setprio(1);
                #pragma unroll
                for (int ks = 0; ks < 2; ++ks) {
                    int off = l15 * 128 + (((ks * 4 + kg) ^ r7) << 4);
                    f16x8 xh = *(const f16x8*)(xr + off);
                    f16x8 xl = *(const f16x8*)(xr + 2048 + off);
                    #pragma unroll
                    for (int g = 0; g < 4; ++g) aH[g] = MFMA16(xh, F0x[g][ks], aH[g]);
                    #pragma unroll
                    for (int g = 0; g < 4; ++g) aL[g] = MFMA16(xl, F0x[g][ks], aL[g]);
                }
                #pragma unroll
                for (int j = 0; j < 3; ++j) {
                    int off = l15 * 256 + (((j * 4 + kg) ^ r7) << 4);
                    f16x8 ah = *(const f16x8*)(h1r + off);
                    #pragma unroll
                    for (int g = 0; g < 4; ++g) aH[g] = MFMA16(ah, F0h[g][j], aH[g]);
                }
                __builtin_amdgcn_s_setprio(0);
                // in-register EW -> h1(s), single f16
                char* h1w = LDS + H1PAN + ((s & 1) << 12);
                #pragma unroll
                for (int q = 0; q < 4; ++q) {
                    float pi = aH[0][q] + aL[0][q] * INV4096;
                    float pf = aH[1][q] + aL[1][q] * INV4096;
                    float pg = aH[2][q] + aL[2][q] * INV4096;
                    float po = aH[3][q] + aL[3][q] * INV4096;
                    float iv = sigf(pi), fv = sigf(pf), gv = tanhf_(pg), ov = sigf(po);
                    float cn = fmaf(fv, c1[q], iv * gv);
                    c1[q] = cn;
                    float h = ov * tanhf_(cn);
                    int r_ = kg * 4 + q;
                    int off = r_ * 256 + ((cb ^ (r_ & 7)) << 4) + lo2;
                    *(unsigned short*)(h1w + off) = f2h_bits(h);
                }
                // write staged x(s+1)
                if (stg && s + 1 < TT) {
                    f16x8 hv, lv;
                    #pragma unroll
                    for (int q = 0; q < 4; ++q) {
                        hv[q] = (_Float16)xa[q];     lv[q] = (_Float16)((xa[q] - (float)hv[q]) * 4096.f);
                        hv[4+q] = (_Float16)xb[q];   lv[4+q] = (_Float16)((xb[q] - (float)hv[4+q]) * 4096.f);
                    }
                    char* xw = LDS + XPAN + (((s + 1) & 1) << 12);
                    *(f16x8*)(xw + xoff) = hv;
                    *(f16x8*)(xw + 2048 + xoff) = lv;
                }
            }
            __syncthreads();
        }
    } else {
        // ================= L1 engine =================
        f16x8 F1[4][6];
        #pragma unroll
        for (int g = 0; g < 4; ++g)
            #pragma unroll
            for (int j = 0; j < 6; ++j)
                F1[g][j] = *(const f16x8*)(wsf2 + (120 + j * 24 + g * 6 + ub) * 512 + lane * 8);
        float bias[4];
        #pragma unroll
        for (int g = 0; g < 4; ++g) bias[g] = b1[g * 96 + ub * 16 + l15];

        f32x4 c2 = {0.f, 0.f, 0.f, 0.f};
        __syncthreads();

        #pragma unroll 1
        for (int s = 0; s <= TT; ++s) {
            if (s >= 1) {
                const char* h1r = LDS + H1PAN + (((s & 1) ^ 1) << 12);   // h1(s-1)
                const char* h2r = LDS + H2PAN + ((s & 1) << 12);         // h2(s-2)
                f32x4 a[4];
                #pragma unroll
                for (int g = 0; g < 4; ++g) a[g] = (f32x4){bias[g], bias[g], bias[g], bias[g]};
                __builtin_amdgcn_s_setprio(1);
                #pragma unroll
                for (int j = 0; j < 6; ++j) {
                    const char* pan = (j < 3) ? h1r : h2r;
                    int cc = (j < 3) ? j : j - 3;
                    int off = l15 * 256 + (((cc * 4 + kg) ^ r7) << 4);
                    f16x8 ah = *(const f16x8*)(pan + off);
                    #pragma unroll
                    for (int g = 0; g < 4; ++g) a[g] = MFMA16(ah, F1[g][j], a[g]);
                }
                __builtin_amdgcn_s_setprio(0);
                // in-register EW -> h2(s-1)
                char* h2w = LDS + H2PAN + ((~s & 1) << 12);
                #pragma unroll
                for (int q = 0; q < 4; ++q) {
                    float pi = a[0][q], pf = a[1][q], pg = a[2][q], po = a[3][q];
                    float iv = sigf(pi), fv = sigf(pf), gv = tanhf_(pg), ov = sigf(po);
                    float cn = fmaf(fv, c2[q], iv * gv);
                    c2[q] = cn;
                    float h = ov * tanhf_(cn);
                    int r_ = kg * 4 + q;
                    int off = r_ * 256 + ((cb ^ (r_ & 7)) << 4) + lo2;
                    *(unsigned short*)(h2w + off) = f2h_bits(h);
                    if (s == TT)
                        ((float*)(LDS + H2F32))[(ub * 16 + l15) * 16 + r_] = h;
                }
            }
            __syncthreads();
        }
    }
    __syncthreads();

    // ---------------- MLP head on f32 h2(T-1): h2f[u*16 + r] ----------------
    const float* h2f = (const float*)(LDS + H2F32);
    float* z1 = (float*)(LDS + FCZ);          // [16][96]
    float* z2 = z1 + 1536;
    if (tid < 192) {
        int u = tid % 96, half = tid / 96;
        float s0 = fcb1[u];
        for (int r = half * 8; r < half * 8 + 8; ++r) {
            float s = s0;
            #pragma unroll 4
            for (int k = 0; k < 96; ++k) s += fcW1[u * 96 + k] * h2f[k * 16 + r];
            z1[r * 96 + u] = s > 0.f ? s : 0.01f * s;
        }
    }
    __syncthreads();
    if (tid < 192) {
        int u = tid % 96, half = tid / 96;
        float s0 = fcb2[u];
        for (int r = half * 8; r < half * 8 + 8; ++r) {
            float s = s0;
            #pragma unroll 4
            for (int k = 0; k < 96; ++k) s += fcW2[u * 96 + k] * z1[r * 96 + k];
            z2[r * 96 + u] = s > 0.f ? s : 0.01f * s;
        }
    }
    __syncthreads();
    if (tid < NB) {
        float s = fcb3[0];
        #pragma unroll 4
        for (int k = 0; k < 96; ++k) s += fcW3[k] * z2[tid * 96 + k];
        out[blk * NB + tid] = s;
    }
}

extern "C" void kernel_launch(void* const* d_in, const int* in_sizes, int n_in,
                              void* d_out, int out_size, void* d_ws, size_t ws_size,
                              hipStream_t stream) {
    const float* x    = (const float*)d_in[0];
    const float* Wih0 = (const float*)d_in[1];
    const float* Whh0 = (const float*)d_in[2];
    const float* b0   = (const float*)d_in[3];
    const float* Wih1 = (const float*)d_in[4];
    const float* Whh1 = (const float*)d_in[5];
    const float* b1   = (const float*)d_in[6];
    const float* fcW1 = (const float*)d_in[7];
    const float* fcb1 = (const float*)d_in[8];
    const float* fcW2 = (const float*)d_in[9];
    const float* fcb2 = (const float*)d_in[10];
    const float* fcW3 = (const float*)d_in[11];
    const float* fcb3 = (const float*)d_in[12];

    unsigned short* wsf2 = (unsigned short*)d_ws;   // 264 KB f16 fragment blocks

    prep_frags16<<<264, 512, 0, stream>>>(Wih0, Whh0, Wih1, Whh1, wsf2);
    lstm_main<<<256, NTHR, 0, stream>>>(x, b0, b1, fcW1, fcb1, fcW2, fcb2,
                                        fcW3, fcb3, wsf2, (float*)d_out);
}

// Round 10
// 397.423 us; speedup vs baseline: 9.1372x; 1.1290x over previous
//
#include <hip/hip_runtime.h>
#include <hip/hip_bf16.h>

#define TT 256
#define NB 16
#define NTHR 768

typedef float f32x4 __attribute__((ext_vector_type(4)));
typedef _Float16 f16x8 __attribute__((ext_vector_type(8)));

// ---------------- LDS layout (bytes) ----------------
#define XPAN  0         // 4 KB: x [2 buf][16r x 128B] f16 hi, XOR-swizzled
#define H1PAN 4096      // 8 KB: h1 [2 buf][16r x 256B] f16, XOR-swizzled
#define H2PAN 12288     // 8 KB: h2 same
#define H2F32 20480     // 6 KB: final h2 f32 [u*16+r]
#define FCZ   26624     // 12 KB: FC scratch
#define LDSZ  38912

__device__ __forceinline__ float vexp2(float x) { float r; asm("v_exp_f32 %0, %1" : "=v"(r) : "v"(x)); return r; }
__device__ __forceinline__ float vrcp(float x)  { float r; asm("v_rcp_f32 %0, %1" : "=v"(r) : "v"(x)); return r; }
#define L2E 1.44269504f
__device__ __forceinline__ float sigf(float x)  { return vrcp(1.f + vexp2(x * (-L2E))); }
__device__ __forceinline__ float tanhf_(float x){ return fmaf(2.f, vrcp(1.f + vexp2(x * (-2.f * L2E))), -1.f); }

#define MFMA16(a, b, c) __builtin_amdgcn_mfma_f32_16x16x32_f16(a, b, c, 0, 0, 0)

__device__ __forceinline__ unsigned short f2h_bits(float f) {
    union { _Float16 h; unsigned short u; } cv; cv.h = (_Float16)f; return cv.u;
}

// ---------------- prep16: all f16 weight fragments (verified r8/r9) ----------------
// Block layout: elem e: i=e&7, col=(e>>3)&15, kg=e>>7;
// k = ks*32+kg*8+i; unit = nt*16+col. Lane l reads [l*8 .. l*8+8) -> B-frag.
// slots: L0-x: ks*24+nt (ks 0..1, Wih0); L0-h: 48 + j*24+nt (j 0..2, Whh0);
//        L1:   120 + j*24+nt (j 0..5, Wih1|Whh1)
__global__ void prep_frags16(const float* __restrict__ Wih0, const float* __restrict__ Whh0,
                             const float* __restrict__ Wih1, const float* __restrict__ Whh1,
                             unsigned short* __restrict__ wsf2) {
    int s = blockIdx.x;        // 0..263
    int e = threadIdx.x;       // 0..511
    int i = e & 7, col = (e >> 3) & 15, kg = e >> 7;
    float wv;
    if (s < 48) {
        int ks = s / 24, nt = s % 24;
        int k = ks * 32 + kg * 8 + i, cg = nt * 16 + col;
        wv = Wih0[cg * 64 + k];
    } else if (s < 120) {
        int j = (s - 48) / 24, nt = (s - 48) % 24;
        int k = j * 32 + kg * 8 + i, cg = nt * 16 + col;
        wv = Whh0[cg * 96 + k];
    } else {
        int s2 = s - 120;
        int j = s2 / 24, nt = s2 % 24;
        int k = j * 32 + kg * 8 + i, cg = nt * 16 + col;
        wv = (k < 96) ? Wih1[cg * 96 + k] : Whh1[cg * 96 + (k - 96)];
    }
    wsf2[s * 512 + e] = f2h_bits(wv);
}

// ---------------- main: 12 waves (6 L0 + 6 L1), x-hi only, in-register EW ----------------
__global__ __launch_bounds__(NTHR, 3) void lstm_main(
    const float* __restrict__ x,
    const float* __restrict__ b0, const float* __restrict__ b1,
    const float* __restrict__ fcW1, const float* __restrict__ fcb1,
    const float* __restrict__ fcW2, const float* __restrict__ fcb2,
    const float* __restrict__ fcW3, const float* __restrict__ fcb3,
    const unsigned short* __restrict__ wsf2,
    float* __restrict__ out)
{
    __shared__ __align__(16) char LDS[LDSZ];

    const int tid = threadIdx.x;
    const int lane = tid & 63;
    const int w = tid >> 6;                  // 0..11
    const int isB = (w ^ (w >> 2)) & 1;      // engine: 0=L0 {0,2,5,7,8,10}, 1=L1
    const int ub = w >> 1;                   // unit block 0..5
    const int l15 = lane & 15, kg = lane >> 4, r7 = l15 & 7;
    const int blk = blockIdx.x;
    const float* xblk = x + (size_t)blk * NB * TT * 64;

    // zero h panels (16 KB)
    #pragma unroll 1
    for (int i = tid; i < 4096; i += NTHR) ((int*)(LDS + H1PAN))[i] = 0;

    const int cb = ub * 2 + (l15 >> 3);      // h-write chunk base
    const int lo2 = (l15 & 7) * 2;

    if (!isB) {
        // ================= L0 engine =================
        // x staging: 4 waves x 32 lanes, one 8-f16 chunk each (128 chunks total)
        const int sidx = (w == 0) ? 0 : (w == 2) ? 1 : (w == 5) ? 2 : 3;
        const bool stg = (w == 0 || w == 2 || w == 5 || w == 7) && (lane < 32);
        const int st = sidx * 32 + lane;             // 0..127
        const int sr = st >> 3, su = st & 7;
        const float* xsrc = xblk + (size_t)sr * TT * 64 + su * 8;
        const int xoff = sr * 128 + ((su ^ (sr & 7)) << 4);

        f32x4 xa, xb;
        // stage x(0) into XPAN buf 0
        if (stg) {
            xa = *(const f32x4*)xsrc; xb = *(const f32x4*)(xsrc + 4);
            f16x8 hv;
            #pragma unroll
            for (int q = 0; q < 4; ++q) { hv[q] = (_Float16)xa[q]; hv[4+q] = (_Float16)xb[q]; }
            *(f16x8*)(LDS + XPAN + xoff) = hv;
        }

        f16x8 F0x[4][2], F0h[4][3];
        #pragma unroll
        for (int g = 0; g < 4; ++g) {
            #pragma unroll
            for (int ks = 0; ks < 2; ++ks)
                F0x[g][ks] = *(const f16x8*)(wsf2 + (ks * 24 + g * 6 + ub) * 512 + lane * 8);
            #pragma unroll
            for (int j = 0; j < 3; ++j)
                F0h[g][j] = *(const f16x8*)(wsf2 + (48 + j * 24 + g * 6 + ub) * 512 + lane * 8);
        }
        float bias[4];
        #pragma unroll
        for (int g = 0; g < 4; ++g) bias[g] = b0[g * 96 + ub * 16 + l15];

        f32x4 c1 = {0.f, 0.f, 0.f, 0.f};
        __syncthreads();

        #pragma unroll 1
        for (int s = 0; s <= TT; ++s) {
            if (s < TT) {
                if (stg && s + 1 < TT) {   // issue x(s+1) loads early (T14)
                    const float* xp = xsrc + (size_t)(s + 1) * 64;
                    xa = *(const f32x4*)xp; xb = *(const f32x4*)(xp + 4);
                }
                const char* xr  = LDS + XPAN + ((s & 1) << 11);
                const char* h1r = LDS + H1PAN + (((s & 1) ^ 1) << 12);
                f32x4 a[4];
                #pragma unroll
                for (int g = 0; g < 4; ++g) a[g] = (f32x4){bias[g], bias[g], bias[g], bias[g]};
                __builtin_amdgcn_s_setprio(1);
                #pragma unroll
                for (int ks = 0; ks < 2; ++ks) {
                    int off = l15 * 128 + (((ks * 4 + kg) ^ r7) << 4);
                    f16x8 xh = *(const f16x8*)(xr + off);
                    #pragma unroll
                    for (int g = 0; g < 4; ++g) a[g] = MFMA16(xh, F0x[g][ks], a[g]);
                }
                #pragma unroll
                for (int j = 0; j < 3; ++j) {
                    int off = l15 * 256 + (((j * 4 + kg) ^ r7) << 4);
                    f16x8 ah = *(const f16x8*)(h1r + off);
                    #pragma unroll
                    for (int g = 0; g < 4; ++g) a[g] = MFMA16(ah, F0h[g][j], a[g]);
                }
                __builtin_amdgcn_s_setprio(0);
                // in-register EW -> h1(s)
                char* h1w = LDS + H1PAN + ((s & 1) << 12);
                #pragma unroll
                for (int q = 0; q < 4; ++q) {
                    float iv = sigf(a[0][q]), fv = sigf(a[1][q]);
                    float gv = tanhf_(a[2][q]), ov = sigf(a[3][q]);
                    float cn = fmaf(fv, c1[q], iv * gv);
                    c1[q] = cn;
                    float h = ov * tanhf_(cn);
                    int r_ = kg * 4 + q;
                    int off = r_ * 256 + ((cb ^ (r_ & 7)) << 4) + lo2;
                    *(unsigned short*)(h1w + off) = f2h_bits(h);
                }
                // write staged x(s+1)
                if (stg && s + 1 < TT) {
                    f16x8 hv;
                    #pragma unroll
                    for (int q = 0; q < 4; ++q) { hv[q] = (_Float16)xa[q]; hv[4+q] = (_Float16)xb[q]; }
                    *(f16x8*)(LDS + XPAN + (((s + 1) & 1) << 11) + xoff) = hv;
                }
            }
            __syncthreads();
        }
    } else {
        // ================= L1 engine =================
        f16x8 F1[4][6];
        #pragma unroll
        for (int g = 0; g < 4; ++g)
            #pragma unroll
            for (int j = 0; j < 6; ++j)
                F1[g][j] = *(const f16x8*)(wsf2 + (120 + j * 24 + g * 6 + ub) * 512 + lane * 8);
        float bias[4];
        #pragma unroll
        for (int g = 0; g < 4; ++g) bias[g] = b1[g * 96 + ub * 16 + l15];

        f32x4 c2 = {0.f, 0.f, 0.f, 0.f};
        __syncthreads();

        #pragma unroll 1
        for (int s = 0; s <= TT; ++s) {
            if (s >= 1) {
                const char* h1r = LDS + H1PAN + (((s & 1) ^ 1) << 12);   // h1(s-1)
                const char* h2r = LDS + H2PAN + ((s & 1) << 12);         // h2(s-2)
                f32x4 a[4];
                #pragma unroll
                for (int g = 0; g < 4; ++g) a[g] = (f32x4){bias[g], bias[g], bias[g], bias[g]};
                __builtin_amdgcn_s_setprio(1);
                #pragma unroll
                for (int j = 0; j < 6; ++j) {
                    const char* pan = (j < 3) ? h1r : h2r;
                    int cc = (j < 3) ? j : j - 3;
                    int off = l15 * 256 + (((cc * 4 + kg) ^ r7) << 4);
                    f16x8 ah = *(const f16x8*)(pan + off);
                    #pragma unroll
                    for (int g = 0; g < 4; ++g) a[g] = MFMA16(ah, F1[g][j], a[g]);
                }
                __builtin_amdgcn_s_setprio(0);
                // in-register EW -> h2(s-1)
                char* h2w = LDS + H2PAN + ((~s & 1) << 12);
                #pragma unroll
                for (int q = 0; q < 4; ++q) {
                    float iv = sigf(a[0][q]), fv = sigf(a[1][q]);
                    float gv = tanhf_(a[2][q]), ov = sigf(a[3][q]);
                    float cn = fmaf(fv, c2[q], iv * gv);
                    c2[q] = cn;
                    float h = ov * tanhf_(cn);
                    int r_ = kg * 4 + q;
                    int off = r_ * 256 + ((cb ^ (r_ & 7)) << 4) + lo2;
                    *(unsigned short*)(h2w + off) = f2h_bits(h);
                    if (s == TT)
                        ((float*)(LDS + H2F32))[(ub * 16 + l15) * 16 + r_] = h;
                }
            }
            __syncthreads();
        }
    }
    __syncthreads();

    // ---------------- MLP head on f32 h2(T-1): h2f[u*16 + r] ----------------
    const float* h2f = (const float*)(LDS + H2F32);
    float* z1 = (float*)(LDS + FCZ);          // [16][96]
    float* z2 = z1 + 1536;
    if (tid < 192) {
        int u = tid % 96, half = tid / 96;
        float s0 = fcb1[u];
        for (int r = half * 8; r < half * 8 + 8; ++r) {
            float s = s0;
            #pragma unroll 4
            for (int k = 0; k < 96; ++k) s += fcW1[u * 96 + k] * h2f[k * 16 + r];
            z1[r * 96 + u] = s > 0.f ? s : 0.01f * s;
        }
    }
    __syncthreads();
    if (tid < 192) {
        int u = tid % 96, half = tid / 96;
        float s0 = fcb2[u];
        for (int r = half * 8; r < half * 8 + 8; ++r) {
            float s = s0;
            #pragma unroll 4
            for (int k = 0; k < 96; ++k) s += fcW2[u * 96 + k] * z1[r * 96 + k];
            z2[r * 96 + u] = s > 0.f ? s : 0.01f * s;
        }
    }
    __syncthreads();
    if (tid < NB) {
        float s = fcb3[0];
        #pragma unroll 4
        for (int k = 0; k < 96; ++k) s += fcW3[k] * z2[tid * 96 + k];
        out[blk * NB + tid] = s;
    }
}

extern "C" void kernel_launch(void* const* d_in, const int* in_sizes, int n_in,
                              void* d_out, int out_size, void* d_ws, size_t ws_size,
                              hipStream_t stream) {
    const float* x    = (const float*)d_in[0];
    const float* Wih0 = (const float*)d_in[1];
    const float* Whh0 = (const float*)d_in[2];
    const float* b0   = (const float*)d_in[3];
    const float* Wih1 = (const float*)d_in[4];
    const float* Whh1 = (const float*)d_in[5];
    const float* b1   = (const float*)d_in[6];
    const float* fcW1 = (const float*)d_in[7];
    const float* fcb1 = (const float*)d_in[8];
    const float* fcW2 = (const float*)d_in[9];
    const float* fcb2 = (const float*)d_in[10];
    const float* fcW3 = (const float*)d_in[11];
    const float* fcb3 = (const float*)d_in[12];

    unsigned short* wsf2 = (unsigned short*)d_ws;   // 264 KB f16 fragment blocks

    prep_frags16<<<264, 512, 0, stream>>>(Wih0, Whh0, Wih1, Whh1, wsf2);
    lstm_main<<<256, NTHR, 0, stream>>>(x, b0, b1, fcW1, fcb1, fcW2, fcb2,
                                        fcW3, fcb3, wsf2, (float*)d_out);
}